// Round 2
// baseline (553.900 us; speedup 1.0000x reference)
//
#include <hip/hip_runtime.h>

typedef unsigned short u16;
typedef __bf16 bf16x8 __attribute__((ext_vector_type(8)));
typedef float f32x4 __attribute__((ext_vector_type(4)));
typedef unsigned short u16x8 __attribute__((ext_vector_type(8)));
typedef unsigned short u16x4 __attribute__((ext_vector_type(4)));

__device__ __forceinline__ u16 f2bf(float f) {
    unsigned u = __builtin_bit_cast(unsigned, f);
    u += 0x7FFFu + ((u >> 16) & 1u);   // RNE
    return (u16)(u >> 16);
}
__device__ __forceinline__ float bf2f(u16 s) {
    return __builtin_bit_cast(float, ((unsigned)s) << 16);
}

// async 16B global->LDS. LDS dest = wave-uniform base + lane*16B (m97/m104).
__device__ __forceinline__ void gload16(u16* lds, const u16* g) {
    __builtin_amdgcn_global_load_lds(
        (__attribute__((address_space(1))) unsigned*)g,
        (__attribute__((address_space(3))) unsigned*)lds,
        16, 0, 0);
}

#define BM 128
#define BN 128
#define BK 32
// Linear LDS tile [128][32] u16 (64B rows) — required by global_load_lds.

// Stage a 128x32 u16 tile from src (row stride ld, k-offset k0) into linear lds.
// 512 segments of 16B; wave w issue i covers segs [w*64 + i*256, +64).
__device__ __forceinline__ void stage_tile(u16* lds, const u16* src, long long ld,
                                           int k0, int wseg0, int lane)
{
#pragma unroll
    for (int i = 0; i < 2; ++i) {
        const int segb = wseg0 + i * 256;      // wave-uniform
        const int seg  = segb + lane;          // per-lane
        const int r = seg >> 2;
        const int c = (seg & 3) << 3;
        gload16(lds + segb * 8, src + (long long)r * ld + k0 + c);
    }
}

__device__ __forceinline__ bf16x8 frag(const u16* lds, int row, int quad) {
    return __builtin_bit_cast(bf16x8, *(const u16x8*)(lds + row * BK + quad * 8));
}

// ---------- emulated-fp32 GEMM, 3 terms interleaved per K-tile ----------
// acc += Al*Bh + Ah*Bl + Ah*Bh per tile (bitwise-identical order to the
// verified 798us gemm_nt3). 48 MFMA per barrier pair.
// SPLITOUT: write C as bf16 hi (C) + lo (Cl); else fp32 to C.
template<bool SPLITOUT>
__global__ void gemm_cat3(const u16* __restrict__ Ah, const u16* __restrict__ Al,
                          const u16* __restrict__ Bh, const u16* __restrict__ Bl,
                          const float* __restrict__ bias,
                          void* __restrict__ C, u16* __restrict__ Cl,
                          int K, long long lda, long long ldb, long long ldc)
{
    __shared__ u16 Ahs[BM * BK];
    __shared__ u16 Als[BM * BK];
    __shared__ u16 Bhs[BN * BK];
    __shared__ u16 Bls[BN * BK];
    const int t = threadIdx.x;
    const int wave = t >> 6, lane = t & 63, quad = lane >> 4, l16 = lane & 15;
    const int wseg0 = wave * 64;
    const int waveM = (wave & 1) * 64, waveN = (wave >> 1) * 64;
    const long long rowBase = (long long)blockIdx.y * BM;
    const long long colBase = (long long)blockIdx.x * BN;
    Ah += rowBase * lda; Al += rowBase * lda;
    Bh += colBase * ldb; Bl += colBase * ldb;

    f32x4 acc[4][4];
#pragma unroll
    for (int i = 0; i < 4; ++i)
#pragma unroll
        for (int j = 0; j < 4; ++j) acc[i][j] = (f32x4){0.f, 0.f, 0.f, 0.f};

    for (int k0 = 0; k0 < K; k0 += BK) {
        __syncthreads();
        stage_tile(Ahs, Ah, lda, k0, wseg0, lane);
        stage_tile(Als, Al, lda, k0, wseg0, lane);
        stage_tile(Bhs, Bh, ldb, k0, wseg0, lane);
        stage_tile(Bls, Bl, ldb, k0, wseg0, lane);
        __syncthreads();

        bf16x8 ah[4], al[4], bh[4], bl[4];
#pragma unroll
        for (int mi = 0; mi < 4; ++mi) {
            int row = waveM + mi * 16 + l16;
            ah[mi] = frag(Ahs, row, quad);
            al[mi] = frag(Als, row, quad);
        }
#pragma unroll
        for (int ni = 0; ni < 4; ++ni) {
            int row = waveN + ni * 16 + l16;
            bh[ni] = frag(Bhs, row, quad);
            bl[ni] = frag(Bls, row, quad);
        }
#pragma unroll
        for (int mi = 0; mi < 4; ++mi)
#pragma unroll
            for (int ni = 0; ni < 4; ++ni) {
                acc[mi][ni] = __builtin_amdgcn_mfma_f32_16x16x32_bf16(al[mi], bh[ni], acc[mi][ni], 0, 0, 0);
                acc[mi][ni] = __builtin_amdgcn_mfma_f32_16x16x32_bf16(ah[mi], bl[ni], acc[mi][ni], 0, 0, 0);
                acc[mi][ni] = __builtin_amdgcn_mfma_f32_16x16x32_bf16(ah[mi], bh[ni], acc[mi][ni], 0, 0, 0);
            }
    }

#pragma unroll
    for (int mi = 0; mi < 4; ++mi) {
#pragma unroll
        for (int ni = 0; ni < 4; ++ni) {
            long long col = colBase + waveN + ni * 16 + l16;
            float bv = bias ? bias[col] : 0.0f;
#pragma unroll
            for (int r = 0; r < 4; ++r) {
                long long row = rowBase + waveM + mi * 16 + quad * 4 + r;
                float f = acc[mi][ni][r] + bv;
                long long off = row * ldc + col;
                if (SPLITOUT) {
                    u16 h = f2bf(f);
                    ((u16*)C)[off] = h;
                    Cl[off] = f2bf(f - bf2f(h));
                } else {
                    ((float*)C)[off] = f;
                }
            }
        }
    }
}

// ---------- single-precision bf16 GEMM: C = A * B^T (+bias) ----------
template<bool OUTF32>
__global__ void gemm_bf(const u16* __restrict__ A, const u16* __restrict__ B,
                        const float* __restrict__ bias, void* __restrict__ C,
                        int K, long long lda, long long ldb, long long ldc)
{
    __shared__ u16 As[BM * BK];
    __shared__ u16 Bs[BN * BK];
    const int t = threadIdx.x;
    const int wave = t >> 6, lane = t & 63, quad = lane >> 4, l16 = lane & 15;
    const int wseg0 = wave * 64;
    const int waveM = (wave & 1) * 64, waveN = (wave >> 1) * 64;
    const long long rowBase = (long long)blockIdx.y * BM;
    const long long colBase = (long long)blockIdx.x * BN;
    A += rowBase * lda;
    B += colBase * ldb;

    f32x4 acc[4][4];
#pragma unroll
    for (int i = 0; i < 4; ++i)
#pragma unroll
        for (int j = 0; j < 4; ++j) acc[i][j] = (f32x4){0.f, 0.f, 0.f, 0.f};

    for (int k0 = 0; k0 < K; k0 += BK) {
        __syncthreads();
        stage_tile(As, A, lda, k0, wseg0, lane);
        stage_tile(Bs, B, ldb, k0, wseg0, lane);
        __syncthreads();

        bf16x8 af[4], bfr[4];
#pragma unroll
        for (int mi = 0; mi < 4; ++mi) af[mi]  = frag(As, waveM + mi * 16 + l16, quad);
#pragma unroll
        for (int ni = 0; ni < 4; ++ni) bfr[ni] = frag(Bs, waveN + ni * 16 + l16, quad);
#pragma unroll
        for (int mi = 0; mi < 4; ++mi)
#pragma unroll
            for (int ni = 0; ni < 4; ++ni)
                acc[mi][ni] = __builtin_amdgcn_mfma_f32_16x16x32_bf16(af[mi], bfr[ni], acc[mi][ni], 0, 0, 0);
    }

#pragma unroll
    for (int mi = 0; mi < 4; ++mi) {
#pragma unroll
        for (int ni = 0; ni < 4; ++ni) {
            long long col = colBase + waveN + ni * 16 + l16;
            float bv = bias ? bias[col] : 0.0f;
#pragma unroll
            for (int r = 0; r < 4; ++r) {
                long long row = rowBase + waveM + mi * 16 + quad * 4 + r;
                float f = acc[mi][ni][r] + bv;
                long long off = row * ldc + col;
                if (OUTF32) ((float*)C)[off] = f;
                else        ((u16*)C)[off] = f2bf(f);
            }
        }
    }
}

// ---------- PV GEMM, split-K over grid.z: buf += A * B^T (fp32 atomics) ----
// A = bf16 softmax weights [2048 rows, stride lda], B = MemT [512,4096].
// Each z-block covers K range [z*KSEG, (z+1)*KSEG). buf is [2048,512] fp32,
// zeroed by softmax_rows beforehand.
__global__ void gemm_pv(const u16* __restrict__ A, const u16* __restrict__ B,
                        float* __restrict__ buf, int KSEG,
                        long long lda, long long ldb)
{
    __shared__ u16 As[BM * BK];
    __shared__ u16 Bs[BN * BK];
    const int t = threadIdx.x;
    const int wave = t >> 6, lane = t & 63, quad = lane >> 4, l16 = lane & 15;
    const int wseg0 = wave * 64;
    const int waveM = (wave & 1) * 64, waveN = (wave >> 1) * 64;
    const long long rowBase = (long long)blockIdx.y * BM;
    const long long colBase = (long long)blockIdx.x * BN;
    const int kbase = blockIdx.z * KSEG;
    A += rowBase * lda;
    B += colBase * ldb;

    f32x4 acc[4][4];
#pragma unroll
    for (int i = 0; i < 4; ++i)
#pragma unroll
        for (int j = 0; j < 4; ++j) acc[i][j] = (f32x4){0.f, 0.f, 0.f, 0.f};

    for (int k0 = kbase; k0 < kbase + KSEG; k0 += BK) {
        __syncthreads();
        stage_tile(As, A, lda, k0, wseg0, lane);
        stage_tile(Bs, B, ldb, k0, wseg0, lane);
        __syncthreads();

        bf16x8 af[4], bfr[4];
#pragma unroll
        for (int mi = 0; mi < 4; ++mi) af[mi]  = frag(As, waveM + mi * 16 + l16, quad);
#pragma unroll
        for (int ni = 0; ni < 4; ++ni) bfr[ni] = frag(Bs, waveN + ni * 16 + l16, quad);
#pragma unroll
        for (int mi = 0; mi < 4; ++mi)
#pragma unroll
            for (int ni = 0; ni < 4; ++ni)
                acc[mi][ni] = __builtin_amdgcn_mfma_f32_16x16x32_bf16(af[mi], bfr[ni], acc[mi][ni], 0, 0, 0);
    }

#pragma unroll
    for (int mi = 0; mi < 4; ++mi) {
#pragma unroll
        for (int ni = 0; ni < 4; ++ni) {
            long long col = colBase + waveN + ni * 16 + l16;
#pragma unroll
            for (int r = 0; r < 4; ++r) {
                long long row = rowBase + waveM + mi * 16 + quad * 4 + r;
                atomicAdd(buf + row * 512 + col, acc[mi][ni][r]);
            }
        }
    }
}

// buf [2048,512] fp32 -> dst bf16 (flat 1M elems)
__global__ void cvt_att(const float* __restrict__ buf, u16* __restrict__ dst)
{
    long long i = ((long long)blockIdx.x * 256 + threadIdx.x) * 8;
    float4 a = *(const float4*)(buf + i);
    float4 b = *(const float4*)(buf + i + 4);
    u16x8 v;
    v[0] = f2bf(a.x); v[1] = f2bf(a.y); v[2] = f2bf(a.z); v[3] = f2bf(a.w);
    v[4] = f2bf(b.x); v[5] = f2bf(b.y); v[6] = f2bf(b.z); v[7] = f2bf(b.w);
    *(u16x8*)(dst + i) = v;
}

// ---------- fp32 -> bf16 hi/lo split, 8 elems/thread ----------
__global__ void split32(const float* __restrict__ src, u16* __restrict__ h,
                        u16* __restrict__ l, long long n)
{
    long long i = ((long long)blockIdx.x * blockDim.x + threadIdx.x) * 8;
    if (i >= n) return;
    float4 a = *(const float4*)(src + i);
    float4 b = *(const float4*)(src + i + 4);
    float v[8] = {a.x, a.y, a.z, a.w, b.x, b.y, b.z, b.w};
    u16x8 hv, lv;
#pragma unroll
    for (int j = 0; j < 8; ++j) {
        u16 hh = f2bf(v[j]);
        hv[j] = hh;
        lv[j] = f2bf(v[j] - bf2f(hh));
    }
    *(u16x8*)(h + i) = hv;
    *(u16x8*)(l + i) = lv;
}

// ---------- fp32 -> bf16 (hi only), 8 elems/thread ----------
__global__ void cvt32(const float* __restrict__ src, u16* __restrict__ dst, long long n)
{
    long long i = ((long long)blockIdx.x * blockDim.x + threadIdx.x) * 8;
    if (i >= n) return;
    float4 a = *(const float4*)(src + i);
    float4 b = *(const float4*)(src + i + 4);
    u16x8 v;
    v[0] = f2bf(a.x); v[1] = f2bf(a.y); v[2] = f2bf(a.z); v[3] = f2bf(a.w);
    v[4] = f2bf(b.x); v[5] = f2bf(b.y); v[6] = f2bf(b.z); v[7] = f2bf(b.w);
    *(u16x8*)(dst + i) = v;
}

// src [4096,512] fp32 -> dst [512,4096] bf16 (one batch)
__global__ void transpose_mem(const float* __restrict__ src, u16* __restrict__ dst)
{
    __shared__ u16 tile[64][72];
    const int dBase = blockIdx.x * 64, mBase = blockIdx.y * 64;
    const int t = threadIdx.x;
#pragma unroll
    for (int i = 0; i < 4; ++i) {
        int seg = t + i * 256;
        int r = seg >> 4;
        int c = (seg & 15) << 2;
        float4 v = *(const float4*)(src + (long long)(mBase + r) * 512 + dBase + c);
        tile[r][c]     = f2bf(v.x);
        tile[r][c + 1] = f2bf(v.y);
        tile[r][c + 2] = f2bf(v.z);
        tile[r][c + 3] = f2bf(v.w);
    }
    __syncthreads();
#pragma unroll
    for (int i = 0; i < 2; ++i) {
        int seg = t + i * 256;
        int r = seg >> 3;
        int c = (seg & 7) << 3;
        u16x8 v;
#pragma unroll
        for (int j = 0; j < 8; ++j) v[j] = tile[c + j][r];
        *(u16x8*)(dst + (long long)(dBase + r) * 4096 + mBase + c) = v;
    }
}

// One block per row of 4096 fp32 scores; writes normalized bf16 weights in place
// (first 8KB of the row's 16KB slot; row stride stays 8192 u16).
// Also zeroes this row's 512-float slice of the PV accumulation buffer.
__global__ void softmax_rows(float* __restrict__ S, float* __restrict__ buf)
{
    float* p = S + (long long)blockIdx.x * 4096;
    const int t = threadIdx.x;

    // zero PV accumulator row (region is dead: scores GEMM already done)
    *(float2*)(buf + (long long)blockIdx.x * 512 + t * 2) = (float2){0.f, 0.f};

    float4 v[4];
#pragma unroll
    for (int i = 0; i < 4; ++i) v[i] = ((const float4*)p)[t + i * 256];

    float m = -1e30f;
#pragma unroll
    for (int i = 0; i < 4; ++i)
        m = fmaxf(m, fmaxf(fmaxf(v[i].x, v[i].y), fmaxf(v[i].z, v[i].w)));
#pragma unroll
    for (int off = 32; off; off >>= 1) m = fmaxf(m, __shfl_xor(m, off));
    __shared__ float redm[4];
    if ((t & 63) == 0) redm[t >> 6] = m;
    __syncthreads();
    m = fmaxf(fmaxf(redm[0], redm[1]), fmaxf(redm[2], redm[3]));

    float s = 0.f;
#pragma unroll
    for (int i = 0; i < 4; ++i) {
        v[i].x = __expf(v[i].x - m); v[i].y = __expf(v[i].y - m);
        v[i].z = __expf(v[i].z - m); v[i].w = __expf(v[i].w - m);
        s += v[i].x + v[i].y + v[i].z + v[i].w;
    }
#pragma unroll
    for (int off = 32; off; off >>= 1) s += __shfl_xor(s, off);
    __shared__ float reds[4];
    if ((t & 63) == 0) reds[t >> 6] = s;
    __syncthreads();
    s = reds[0] + reds[1] + reds[2] + reds[3];
    const float inv = 1.0f / s;

    u16* pw = (u16*)p;
#pragma unroll
    for (int i = 0; i < 4; ++i) {
        u16x4 w;
        w[0] = f2bf(v[i].x * inv); w[1] = f2bf(v[i].y * inv);
        w[2] = f2bf(v[i].z * inv); w[3] = f2bf(v[i].w * inv);
        *(u16x4*)(pw + 4 * (t + i * 256)) = w;
    }
}

extern "C" void kernel_launch(void* const* d_in, const int* in_sizes, int n_in,
                              void* d_out, int out_size, void* d_ws, size_t ws_size,
                              hipStream_t stream)
{
    const float* x   = (const float*)d_in[0];   // [4,2048,1024] fp32
    const float* mem = (const float*)d_in[1];   // [4,4096,512]  fp32
    const float* Wq  = (const float*)d_in[2];   // [512,1024]    fp32
    const float* bq  = (const float*)d_in[3];   // [512]         fp32
    const float* Wm  = (const float*)d_in[4];   // [1024,512]    fp32
    const float* bm  = (const float*)d_in[5];   // [1024]        fp32

    // d_out (64MB) scratch schedule — every region dead before its final producer:
    //  [ 0, 8)  Qh  bf16 [8192,512]  (cvt_att overwrites batch rows with bf16 Att)
    //  [ 8,16)  Ql  bf16 [8192,512]
    //  [16,24)  Mh/Ml bf16 [4096,512] each (per batch; [16,20) doubles as the
    //           fp32 PV accumulation buffer once Mh is dead post-scores)
    //  [24,28)  MemT bf16 [512,4096]
    //  [28,29)  Wqh, [29,30) Wql, [30,31) Wmh
    //  [32,64)  Xh/Xl (pre-loop) -> Sc fp32 [2048,4096] (in-loop) -> out1 (final)
    char* base = (char*)d_out;
    u16*   Qh   = (u16*)base;
    u16*   Ql   = (u16*)(base + (8ll  << 20));
    u16*   Mh   = (u16*)(base + (16ll << 20));
    u16*   Ml   = (u16*)(base + (20ll << 20));
    float* Abuf = (float*)(base + (16ll << 20));   // aliases Mh (dead post-scores)
    u16*   MemT = (u16*)(base + (24ll << 20));
    u16*   Wqh  = (u16*)(base + (28ll << 20));
    u16*   Wql  = (u16*)(base + (29ll << 20));
    u16*   Wmh  = (u16*)(base + (30ll << 20));
    u16*   Xh   = (u16*)(base + (32ll << 20));
    u16*   Xl   = (u16*)(base + (48ll << 20));
    float* Sc   = (float*)(base + (32ll << 20));
    float* out1 = (float*)d_out + 8388608ll;

    // one-time hi/lo splits (identical rounding to the verified in-GEMM split)
    split32<<<4096, 256, 0, stream>>>(x,  Xh,  Xl,  8192ll * 1024);
    split32<<<256,  256, 0, stream>>>(Wq, Wqh, Wql, 512ll * 1024);
    cvt32<<<256,    256, 0, stream>>>(Wm, Wmh,      1024ll * 512);

    // Qh/Ql = split(x @ Wq^T + bq)   [8192,512], K=1024, 3-term interleaved
    gemm_cat3<true><<<dim3(512 / 128, 8192 / 128), 256, 0, stream>>>(
        Xh, Xl, Wqh, Wql, bq, Qh, Ql, 1024, 1024, 1024, 512);

    for (int b = 0; b < 4; ++b) {
        const float* Mb = mem + (long long)b * 4096 * 512;
        u16* Qhb = Qh + (long long)b * 2048 * 512;
        u16* Qlb = Ql + (long long)b * 2048 * 512;

        split32<<<1024, 256, 0, stream>>>(Mb, Mh, Ml, 4096ll * 512);
        transpose_mem<<<dim3(8, 64), 256, 0, stream>>>(Mb, MemT);

        // Sc = Qb @ Mb^T  [2048,4096], K=512, 3-term interleaved, fp32-precision
        gemm_cat3<false><<<dim3(4096 / 128, 2048 / 128), 256, 0, stream>>>(
            Qhb, Qlb, Mh, Ml, nullptr, Sc, nullptr, 512, 512, 512, 4096);

        // softmax rows -> bf16 weights in place; zeroes Abuf (Mh now dead)
        softmax_rows<<<dim3(2048), 256, 0, stream>>>(Sc, Abuf);

        // Abuf += W @ MemT^T, split-K x4: grid (4,16,4) = 256 blocks
        gemm_pv<<<dim3(512 / 128, 2048 / 128, 4), 256, 0, stream>>>(
            (const u16*)Sc, MemT, Abuf, 1024, 8192, 4096);

        // bf16(Abuf) -> dead Q rows (ldc=512 contiguous)
        cvt_att<<<dim3(512), 256, 0, stream>>>(Abuf, Qhb);
    }

    // out1 = Att @ Wm^T + bm   [8192,1024], K=512; A = Qh rows, lda=512
    gemm_bf<true><<<dim3(1024 / 128, 8192 / 128), 256, 0, stream>>>(
        Qh, Wmh, bm, out1, 512, 512, 512, 1024);

    // out0 = x (exact fp32 copy; overwrites dead scratch in [0,32MB)). Must be last.
    hipMemcpyAsync(d_out, x, 8192ll * 1024 * 4, hipMemcpyDeviceToDevice, stream);
}

// Round 7
// 534.269 us; speedup vs baseline: 1.0367x; 1.0367x over previous
//
#include <hip/hip_runtime.h>

typedef unsigned short u16;
typedef __bf16 bf16x8 __attribute__((ext_vector_type(8)));
typedef float f32x4 __attribute__((ext_vector_type(4)));
typedef unsigned short u16x8 __attribute__((ext_vector_type(8)));
typedef unsigned short u16x4 __attribute__((ext_vector_type(4)));

__device__ __forceinline__ u16 f2bf(float f) {
    unsigned u = __builtin_bit_cast(unsigned, f);
    u += 0x7FFFu + ((u >> 16) & 1u);   // RNE
    return (u16)(u >> 16);
}
__device__ __forceinline__ float bf2f(u16 s) {
    return __builtin_bit_cast(float, ((unsigned)s) << 16);
}

// async 16B global->LDS. LDS dest = wave-uniform base + lane*16B (m97/m104).
__device__ __forceinline__ void gload16(u16* lds, const u16* g) {
    __builtin_amdgcn_global_load_lds(
        (__attribute__((address_space(1))) unsigned*)g,
        (__attribute__((address_space(3))) unsigned*)lds,
        16, 0, 0);
}

// XCD-chunked tile remap (T1): dispatch id d -> XCD d&7. Give each XCD a
// cw x ch tile sub-rectangle so its panel working set fits the 4MB L2.
// Requires gridDim.x % xcx == 0, gridDim.y % (8/xcx) == 0, total % 8 == 0.
__device__ __forceinline__ void remap_xy(int xcx, int& bx, int& by) {
    const int nx = gridDim.x;
    const int d = blockIdx.y * nx + blockIdx.x;
    const int xcd = d & 7, i = d >> 3;
    const int xcy = 8 / xcx;
    const int cw = nx / xcx;
    const int ch = (int)gridDim.y / xcy;
    bx = (xcd % xcx) * cw + i % cw;
    by = (xcd / xcx) * ch + i / cw;
}

#define BM 128
#define BN 128
#define BK 32
#define TILE (BM * BK)   // u16 per 128x32 tile
// LDS tile layout: [128][32] u16 linear (64B rows, 4x 16B k-slots per row).
// k-slot swizzle: LDS slot (r, qs) holds global k-slot qs ^ ((r>>1)&3).
// Applied on the GLOBAL source in staging (LDS dest must stay linear for
// global_load_lds) and with the same XOR on the read (rule #21 both-sides).
// Each quarter-wave's 16 ds_read_b128 then cover all 32 banks at 2 lanes/bank
// (free, m136) instead of 8 lanes/bank.

// Stage a 128x32 u16 tile from src (row stride ld, k-offset k0) into linear lds.
// 512 segments of 16B; wave w issue i covers segs [w*64 + i*256, +64).
__device__ __forceinline__ void stage_tile(u16* lds, const u16* src, long long ld,
                                           int k0, int wseg0, int lane)
{
#pragma unroll
    for (int i = 0; i < 2; ++i) {
        const int segb = wseg0 + i * 256;      // wave-uniform
        const int seg  = segb + lane;          // per-lane
        const int r  = seg >> 2;
        const int qs = seg & 3;
        const int qg = qs ^ ((r >> 1) & 3);    // pre-swizzled global k-slot
        gload16(lds + segb * 8, src + (long long)r * ld + k0 + qg * 8);
    }
}

__device__ __forceinline__ bf16x8 frag(const u16* lds, int row, int quad) {
    const int slot = quad ^ ((row >> 1) & 3);  // matching read-side swizzle
    return __builtin_bit_cast(bf16x8, *(const u16x8*)(lds + row * BK + slot * 8));
}

// ---------- emulated-fp32 GEMM, 3 terms interleaved per K-tile ----------
// acc += Al*Bh + Ah*Bl + Ah*Bh per tile (bitwise-identical order to the
// verified gemm_nt3). Double-buffered LDS, prefetch-before-compute,
// ONE barrier per K-tile: stage latency hides under 48 MFMA.
// SPLITOUT: write C as bf16 hi (C) + lo (Cl); else fp32 to C.
template<bool SPLITOUT>
__global__ void gemm_cat3(const u16* __restrict__ Ah, const u16* __restrict__ Al,
                          const u16* __restrict__ Bh, const u16* __restrict__ Bl,
                          const float* __restrict__ bias,
                          void* __restrict__ C, u16* __restrict__ Cl,
                          int K, long long lda, long long ldb, long long ldc,
                          int xcx)
{
    __shared__ u16 sm[2][4][TILE];   // 64KB: {Ah,Al,Bh,Bl} x dbuf
    const int t = threadIdx.x;
    const int wave = t >> 6, lane = t & 63, quad = lane >> 4, l16 = lane & 15;
    const int wseg0 = wave * 64;
    const int waveM = (wave & 1) * 64, waveN = (wave >> 1) * 64;
    int bx, by;
    remap_xy(xcx, bx, by);
    const long long rowBase = (long long)by * BM;
    const long long colBase = (long long)bx * BN;
    Ah += rowBase * lda; Al += rowBase * lda;
    Bh += colBase * ldb; Bl += colBase * ldb;

    f32x4 acc[4][4];
#pragma unroll
    for (int i = 0; i < 4; ++i)
#pragma unroll
        for (int j = 0; j < 4; ++j) acc[i][j] = (f32x4){0.f, 0.f, 0.f, 0.f};

    auto stage4 = [&](int buf, int k0) {
        stage_tile(sm[buf][0], Ah, lda, k0, wseg0, lane);
        stage_tile(sm[buf][1], Al, lda, k0, wseg0, lane);
        stage_tile(sm[buf][2], Bh, ldb, k0, wseg0, lane);
        stage_tile(sm[buf][3], Bl, ldb, k0, wseg0, lane);
    };

    stage4(0, 0);
    __syncthreads();
    int cur = 0;
    for (int k0 = 0; k0 < K; k0 += BK) {
        if (k0 + BK < K) stage4(cur ^ 1, k0 + BK);   // prefetch next tile

        bf16x8 ah[4], al[4], bh[4], bl[4];
#pragma unroll
        for (int mi = 0; mi < 4; ++mi) {
            int row = waveM + mi * 16 + l16;
            ah[mi] = frag(sm[cur][0], row, quad);
            al[mi] = frag(sm[cur][1], row, quad);
        }
#pragma unroll
        for (int ni = 0; ni < 4; ++ni) {
            int row = waveN + ni * 16 + l16;
            bh[ni] = frag(sm[cur][2], row, quad);
            bl[ni] = frag(sm[cur][3], row, quad);
        }
#pragma unroll
        for (int mi = 0; mi < 4; ++mi)
#pragma unroll
            for (int ni = 0; ni < 4; ++ni) {
                acc[mi][ni] = __builtin_amdgcn_mfma_f32_16x16x32_bf16(al[mi], bh[ni], acc[mi][ni], 0, 0, 0);
                acc[mi][ni] = __builtin_amdgcn_mfma_f32_16x16x32_bf16(ah[mi], bl[ni], acc[mi][ni], 0, 0, 0);
                acc[mi][ni] = __builtin_amdgcn_mfma_f32_16x16x32_bf16(ah[mi], bh[ni], acc[mi][ni], 0, 0, 0);
            }

        __syncthreads();   // drains this iter's prefetch (vmcnt 0) + barrier
        cur ^= 1;
    }

#pragma unroll
    for (int mi = 0; mi < 4; ++mi) {
#pragma unroll
        for (int ni = 0; ni < 4; ++ni) {
            long long col = colBase + waveN + ni * 16 + l16;
            float bv = bias ? bias[col] : 0.0f;
#pragma unroll
            for (int r = 0; r < 4; ++r) {
                long long row = rowBase + waveM + mi * 16 + quad * 4 + r;
                float f = acc[mi][ni][r] + bv;
                long long off = row * ldc + col;
                if (SPLITOUT) {
                    u16 h = f2bf(f);
                    ((u16*)C)[off] = h;
                    Cl[off] = f2bf(f - bf2f(h));
                } else {
                    ((float*)C)[off] = f;
                }
            }
        }
    }
}

// ---------- single-precision bf16 GEMM: C = A * B^T (+bias), dbuf ----------
template<bool OUTF32>
__global__ void gemm_bf(const u16* __restrict__ A, const u16* __restrict__ B,
                        const float* __restrict__ bias, void* __restrict__ C,
                        int K, long long lda, long long ldb, long long ldc,
                        int xcx)
{
    __shared__ u16 sm[2][2][TILE];   // 32KB
    const int t = threadIdx.x;
    const int wave = t >> 6, lane = t & 63, quad = lane >> 4, l16 = lane & 15;
    const int wseg0 = wave * 64;
    const int waveM = (wave & 1) * 64, waveN = (wave >> 1) * 64;
    int bx, by;
    remap_xy(xcx, bx, by);
    const long long rowBase = (long long)by * BM;
    const long long colBase = (long long)bx * BN;
    A += rowBase * lda;
    B += colBase * ldb;

    f32x4 acc[4][4];
#pragma unroll
    for (int i = 0; i < 4; ++i)
#pragma unroll
        for (int j = 0; j < 4; ++j) acc[i][j] = (f32x4){0.f, 0.f, 0.f, 0.f};

    auto stage2 = [&](int buf, int k0) {
        stage_tile(sm[buf][0], A, lda, k0, wseg0, lane);
        stage_tile(sm[buf][1], B, ldb, k0, wseg0, lane);
    };

    stage2(0, 0);
    __syncthreads();
    int cur = 0;
    for (int k0 = 0; k0 < K; k0 += BK) {
        if (k0 + BK < K) stage2(cur ^ 1, k0 + BK);

        bf16x8 af[4], bfr[4];
#pragma unroll
        for (int mi = 0; mi < 4; ++mi) af[mi]  = frag(sm[cur][0], waveM + mi * 16 + l16, quad);
#pragma unroll
        for (int ni = 0; ni < 4; ++ni) bfr[ni] = frag(sm[cur][1], waveN + ni * 16 + l16, quad);
#pragma unroll
        for (int mi = 0; mi < 4; ++mi)
#pragma unroll
            for (int ni = 0; ni < 4; ++ni)
                acc[mi][ni] = __builtin_amdgcn_mfma_f32_16x16x32_bf16(af[mi], bfr[ni], acc[mi][ni], 0, 0, 0);

        __syncthreads();
        cur ^= 1;
    }

#pragma unroll
    for (int mi = 0; mi < 4; ++mi) {
#pragma unroll
        for (int ni = 0; ni < 4; ++ni) {
            long long col = colBase + waveN + ni * 16 + l16;
            float bv = bias ? bias[col] : 0.0f;
#pragma unroll
            for (int r = 0; r < 4; ++r) {
                long long row = rowBase + waveM + mi * 16 + quad * 4 + r;
                float f = acc[mi][ni][r] + bv;
                long long off = row * ldc + col;
                if (OUTF32) ((float*)C)[off] = f;
                else        ((u16*)C)[off] = f2bf(f);
            }
        }
    }
}

// ---------- PV GEMM, split-K over grid.z: buf += A * B^T (fp32 atomics) ----
__global__ void gemm_pv(const u16* __restrict__ A, const u16* __restrict__ B,
                        float* __restrict__ buf, int KSEG,
                        long long lda, long long ldb)
{
    __shared__ u16 sm[2][2][TILE];   // 32KB
    const int t = threadIdx.x;
    const int wave = t >> 6, lane = t & 63, quad = lane >> 4, l16 = lane & 15;
    const int wseg0 = wave * 64;
    const int waveM = (wave & 1) * 64, waveN = (wave >> 1) * 64;
    const long long rowBase = (long long)blockIdx.y * BM;
    const long long colBase = (long long)blockIdx.x * BN;
    const int kbase = blockIdx.z * KSEG;
    A += rowBase * lda;
    B += colBase * ldb;

    f32x4 acc[4][4];
#pragma unroll
    for (int i = 0; i < 4; ++i)
#pragma unroll
        for (int j = 0; j < 4; ++j) acc[i][j] = (f32x4){0.f, 0.f, 0.f, 0.f};

    auto stage2 = [&](int buf_, int k0) {
        stage_tile(sm[buf_][0], A, lda, k0, wseg0, lane);
        stage_tile(sm[buf_][1], B, ldb, k0, wseg0, lane);
    };

    stage2(0, kbase);
    __syncthreads();
    int cur = 0;
    for (int k0 = kbase; k0 < kbase + KSEG; k0 += BK) {
        if (k0 + BK < kbase + KSEG) stage2(cur ^ 1, k0 + BK);

        bf16x8 af[4], bfr[4];
#pragma unroll
        for (int mi = 0; mi < 4; ++mi) af[mi]  = frag(sm[cur][0], waveM + mi * 16 + l16, quad);
#pragma unroll
        for (int ni = 0; ni < 4; ++ni) bfr[ni] = frag(sm[cur][1], waveN + ni * 16 + l16, quad);
#pragma unroll
        for (int mi = 0; mi < 4; ++mi)
#pragma unroll
            for (int ni = 0; ni < 4; ++ni)
                acc[mi][ni] = __builtin_amdgcn_mfma_f32_16x16x32_bf16(af[mi], bfr[ni], acc[mi][ni], 0, 0, 0);

        __syncthreads();
        cur ^= 1;
    }

#pragma unroll
    for (int mi = 0; mi < 4; ++mi) {
#pragma unroll
        for (int ni = 0; ni < 4; ++ni) {
            long long col = colBase + waveN + ni * 16 + l16;
#pragma unroll
            for (int r = 0; r < 4; ++r) {
                long long row = rowBase + waveM + mi * 16 + quad * 4 + r;
                atomicAdd(buf + row * 512 + col, acc[mi][ni][r]);
            }
        }
    }
}

// buf [2048,512] fp32 -> dst bf16 (flat 1M elems)
__global__ void cvt_att(const float* __restrict__ buf, u16* __restrict__ dst)
{
    long long i = ((long long)blockIdx.x * 256 + threadIdx.x) * 8;
    float4 a = *(const float4*)(buf + i);
    float4 b = *(const float4*)(buf + i + 4);
    u16x8 v;
    v[0] = f2bf(a.x); v[1] = f2bf(a.y); v[2] = f2bf(a.z); v[3] = f2bf(a.w);
    v[4] = f2bf(b.x); v[5] = f2bf(b.y); v[6] = f2bf(b.z); v[7] = f2bf(b.w);
    *(u16x8*)(dst + i) = v;
}

// ---------- fp32 -> bf16 hi/lo split, 8 elems/thread ----------
__global__ void split32(const float* __restrict__ src, u16* __restrict__ h,
                        u16* __restrict__ l, long long n)
{
    long long i = ((long long)blockIdx.x * blockDim.x + threadIdx.x) * 8;
    if (i >= n) return;
    float4 a = *(const float4*)(src + i);
    float4 b = *(const float4*)(src + i + 4);
    float v[8] = {a.x, a.y, a.z, a.w, b.x, b.y, b.z, b.w};
    u16x8 hv, lv;
#pragma unroll
    for (int j = 0; j < 8; ++j) {
        u16 hh = f2bf(v[j]);
        hv[j] = hh;
        lv[j] = f2bf(v[j] - bf2f(hh));
    }
    *(u16x8*)(h + i) = hv;
    *(u16x8*)(l + i) = lv;
}

// ---------- fp32 -> bf16 (hi only), 8 elems/thread ----------
__global__ void cvt32(const float* __restrict__ src, u16* __restrict__ dst, long long n)
{
    long long i = ((long long)blockIdx.x * blockDim.x + threadIdx.x) * 8;
    if (i >= n) return;
    float4 a = *(const float4*)(src + i);
    float4 b = *(const float4*)(src + i + 4);
    u16x8 v;
    v[0] = f2bf(a.x); v[1] = f2bf(a.y); v[2] = f2bf(a.z); v[3] = f2bf(a.w);
    v[4] = f2bf(b.x); v[5] = f2bf(b.y); v[6] = f2bf(b.z); v[7] = f2bf(b.w);
    *(u16x8*)(dst + i) = v;
}

// Fused per-batch memory prep: one pass over src [4096,512] fp32 ->
//   Mh/Ml [4096,512] bf16 hi/lo  +  MemT [512,4096] bf16 (transposed hi).
// Same f2bf rounding as split32/transpose_mem (bit-identical outputs).
__global__ void prep_mem(const float* __restrict__ src, u16* __restrict__ h,
                         u16* __restrict__ l, u16* __restrict__ tdst)
{
    __shared__ u16 tile[64][72];
    const int dBase = blockIdx.x * 64, mBase = blockIdx.y * 64;
    const int t = threadIdx.x;
#pragma unroll
    for (int i = 0; i < 4; ++i) {
        int seg = t + i * 256;
        int r = seg >> 4;                 // m-local
        int c = (seg & 15) << 2;          // d-local
        long long off = (long long)(mBase + r) * 512 + dBase + c;
        float4 v = *(const float4*)(src + off);
        u16 h0 = f2bf(v.x), h1 = f2bf(v.y), h2 = f2bf(v.z), h3 = f2bf(v.w);
        tile[r][c] = h0; tile[r][c + 1] = h1; tile[r][c + 2] = h2; tile[r][c + 3] = h3;
        u16x4 hv; hv[0] = h0; hv[1] = h1; hv[2] = h2; hv[3] = h3;
        u16x4 lv;
        lv[0] = f2bf(v.x - bf2f(h0)); lv[1] = f2bf(v.y - bf2f(h1));
        lv[2] = f2bf(v.z - bf2f(h2)); lv[3] = f2bf(v.w - bf2f(h3));
        *(u16x4*)(h + off) = hv;
        *(u16x4*)(l + off) = lv;
    }
    __syncthreads();
#pragma unroll
    for (int i = 0; i < 2; ++i) {
        int seg = t + i * 256;
        int r = seg >> 3;          // d-local
        int c = (seg & 7) << 3;    // m-local
        u16x8 v;
#pragma unroll
        for (int j = 0; j < 8; ++j) v[j] = tile[c + j][r];
        *(u16x8*)(tdst + (long long)(dBase + r) * 4096 + mBase + c) = v;
    }
}

// One block per row of 4096 fp32 scores; writes normalized bf16 weights in place
// (first 8KB of the row's 16KB slot; row stride stays 8192 u16).
// Also zeroes this row's 512-float slice of the PV accumulation buffer.
__global__ void softmax_rows(float* __restrict__ S, float* __restrict__ buf)
{
    float* p = S + (long long)blockIdx.x * 4096;
    const int t = threadIdx.x;

    // zero PV accumulator row (region is dead: scores GEMM already done)
    *(float2*)(buf + (long long)blockIdx.x * 512 + t * 2) = (float2){0.f, 0.f};

    float4 v[4];
#pragma unroll
    for (int i = 0; i < 4; ++i) v[i] = ((const float4*)p)[t + i * 256];

    float m = -1e30f;
#pragma unroll
    for (int i = 0; i < 4; ++i)
        m = fmaxf(m, fmaxf(fmaxf(v[i].x, v[i].y), fmaxf(v[i].z, v[i].w)));
#pragma unroll
    for (int off = 32; off; off >>= 1) m = fmaxf(m, __shfl_xor(m, off));
    __shared__ float redm[4];
    if ((t & 63) == 0) redm[t >> 6] = m;
    __syncthreads();
    m = fmaxf(fmaxf(redm[0], redm[1]), fmaxf(redm[2], redm[3]));

    float s = 0.f;
#pragma unroll
    for (int i = 0; i < 4; ++i) {
        v[i].x = __expf(v[i].x - m); v[i].y = __expf(v[i].y - m);
        v[i].z = __expf(v[i].z - m); v[i].w = __expf(v[i].w - m);
        s += v[i].x + v[i].y + v[i].z + v[i].w;
    }
#pragma unroll
    for (int off = 32; off; off >>= 1) s += __shfl_xor(s, off);
    __shared__ float reds[4];
    if ((t & 63) == 0) reds[t >> 6] = s;
    __syncthreads();
    s = reds[0] + reds[1] + reds[2] + reds[3];
    const float inv = 1.0f / s;

    u16* pw = (u16*)p;
#pragma unroll
    for (int i = 0; i < 4; ++i) {
        u16x4 w;
        w[0] = f2bf(v[i].x * inv); w[1] = f2bf(v[i].y * inv);
        w[2] = f2bf(v[i].z * inv); w[3] = f2bf(v[i].w * inv);
        *(u16x4*)(pw + 4 * (t + i * 256)) = w;
    }
}

extern "C" void kernel_launch(void* const* d_in, const int* in_sizes, int n_in,
                              void* d_out, int out_size, void* d_ws, size_t ws_size,
                              hipStream_t stream)
{
    const float* x   = (const float*)d_in[0];   // [4,2048,1024] fp32
    const float* mem = (const float*)d_in[1];   // [4,4096,512]  fp32
    const float* Wq  = (const float*)d_in[2];   // [512,1024]    fp32
    const float* bq  = (const float*)d_in[3];   // [512]         fp32
    const float* Wm  = (const float*)d_in[4];   // [1024,512]    fp32
    const float* bm  = (const float*)d_in[5];   // [1024]        fp32

    // d_out (64MB) scratch schedule — every region dead before its final producer:
    //  [ 0, 8)  Qh  bf16 [8192,512]  (cvt_att overwrites batch rows with bf16 Att)
    //  [ 8,16)  Ql  bf16 [8192,512]
    //  [16,24)  Mh/Ml bf16 [4096,512] each (per batch; [16,20) doubles as the
    //           fp32 PV accumulation buffer once Mh is dead post-scores)
    //  [24,28)  MemT bf16 [512,4096]
    //  [28,29)  Wqh, [29,30) Wql, [30,31) Wmh
    //  [32,64)  Xh/Xl (pre-loop) -> Sc fp32 [2048,4096] (in-loop) -> out1 (final)
    char* base = (char*)d_out;
    u16*   Qh   = (u16*)base;
    u16*   Ql   = (u16*)(base + (8ll  << 20));
    u16*   Mh   = (u16*)(base + (16ll << 20));
    u16*   Ml   = (u16*)(base + (20ll << 20));
    float* Abuf = (float*)(base + (16ll << 20));   // aliases Mh (dead post-scores)
    u16*   MemT = (u16*)(base + (24ll << 20));
    u16*   Wqh  = (u16*)(base + (28ll << 20));
    u16*   Wql  = (u16*)(base + (29ll << 20));
    u16*   Wmh  = (u16*)(base + (30ll << 20));
    u16*   Xh   = (u16*)(base + (32ll << 20));
    u16*   Xl   = (u16*)(base + (48ll << 20));
    float* Sc   = (float*)(base + (32ll << 20));
    float* out1 = (float*)d_out + 8388608ll;

    // one-time hi/lo splits (identical rounding to the verified in-GEMM split)
    split32<<<4096, 256, 0, stream>>>(x,  Xh,  Xl,  8192ll * 1024);
    split32<<<256,  256, 0, stream>>>(Wq, Wqh, Wql, 512ll * 1024);
    cvt32<<<256,    256, 0, stream>>>(Wm, Wmh,      1024ll * 512);

    // Qh/Ql = split(x @ Wq^T + bq)   [8192,512], K=1024, 3-term interleaved
    // grid (4,64): xcx=1 -> each XCD 8 consecutive row-panels, Wq L2-resident
    gemm_cat3<true><<<dim3(512 / 128, 8192 / 128), 256, 0, stream>>>(
        Xh, Xl, Wqh, Wql, bq, Qh, Ql, 1024, 1024, 1024, 512, 1);

    for (int b = 0; b < 4; ++b) {
        const float* Mb = mem + (long long)b * 4096 * 512;
        u16* Qhb = Qh + (long long)b * 2048 * 512;
        u16* Qlb = Ql + (long long)b * 2048 * 512;

        // fused split + transpose: one pass over Mb
        prep_mem<<<dim3(8, 64), 256, 0, stream>>>(Mb, Mh, Ml, MemT);

        // Sc = Qb @ Mb^T  [2048,4096], K=512, 3-term interleaved, fp32-precision
        // grid (32,16): xcx=4 -> each XCD an 8x8 tile square (2MB A + 2MB B in L2)
        gemm_cat3<false><<<dim3(4096 / 128, 2048 / 128), 256, 0, stream>>>(
            Qhb, Qlb, Mh, Ml, nullptr, Sc, nullptr, 512, 512, 512, 4096, 4);

        // softmax rows -> bf16 weights in place; zeroes Abuf (Mh now dead)
        softmax_rows<<<dim3(2048), 256, 0, stream>>>(Sc, Abuf);

        // Abuf += W @ MemT^T, split-K x8: grid (4,16,8) = 512 blocks
        gemm_pv<<<dim3(512 / 128, 2048 / 128, 8), 256, 0, stream>>>(
            (const u16*)Sc, MemT, Abuf, 512, 8192, 4096);

        // bf16(Abuf) -> dead Q rows (ldc=512 contiguous)
        cvt_att<<<dim3(512), 256, 0, stream>>>(Abuf, Qhb);
    }

    // out1 = Att @ Wm^T + bm   [8192,1024], K=512; A = Qh rows, lda=512
    // grid (8,64): xcx=1 -> Wm L2-resident per XCD
    gemm_bf<true><<<dim3(1024 / 128, 8192 / 128), 256, 0, stream>>>(
        Qh, Wmh, bm, out1, 512, 512, 512, 1024, 1);

    // out0 = x (exact fp32 copy; overwrites dead scratch in [0,32MB)). Must be last.
    hipMemcpyAsync(d_out, x, 8192ll * 1024 * 4, hipMemcpyDeviceToDevice, stream);
}

// Round 9
// 511.263 us; speedup vs baseline: 1.0834x; 1.0450x over previous
//
#include <hip/hip_runtime.h>

typedef unsigned short u16;
typedef __bf16 bf16x8 __attribute__((ext_vector_type(8)));
typedef float f32x4 __attribute__((ext_vector_type(4)));
typedef unsigned short u16x8 __attribute__((ext_vector_type(8)));
typedef unsigned short u16x4 __attribute__((ext_vector_type(4)));

__device__ __forceinline__ u16 f2bf(float f) {
    unsigned u = __builtin_bit_cast(unsigned, f);
    u += 0x7FFFu + ((u >> 16) & 1u);   // RNE
    return (u16)(u >> 16);
}
__device__ __forceinline__ float bf2f(u16 s) {
    return __builtin_bit_cast(float, ((unsigned)s) << 16);
}

// async 16B global->LDS. LDS dest = wave-uniform base + lane*16B (m97/m104).
__device__ __forceinline__ void gload16(u16* lds, const u16* g) {
    __builtin_amdgcn_global_load_lds(
        (__attribute__((address_space(1))) unsigned*)g,
        (__attribute__((address_space(3))) unsigned*)lds,
        16, 0, 0);
}

// XCD-chunked tile remap (T1): dispatch id d -> XCD d&7; each XCD owns a
// cw x ch tile sub-rectangle (verified R7: FETCH 66->25MB).
__device__ __forceinline__ void remap_xy(int xcx, int& bx, int& by) {
    const int nx = gridDim.x;
    const int d = blockIdx.y * nx + blockIdx.x;
    const int xcd = d & 7, i = d >> 3;
    const int xcy = 8 / xcx;
    const int cw = nx / xcx;
    const int ch = (int)gridDim.y / xcy;
    bx = (xcd % xcx) * cw + i % cw;
    by = (xcd / xcx) * ch + i / cw;
}

// R8: BM 128->64. Rationale: cat3 hit the 2-phase ceiling (635 TF) with
// grid-capped 2 blocks/CU in lockstep at the barrier drain; 64-row tiles
// double the grid (scores 1024 blocks) and cut LDS to 48KB -> 3 blocks/CU
// co-resident, desynced barriers overlap the load latency.
#define BM 64
#define BN 128
#define BK 32
#define TILE_A (BM * BK)   // 2048 u16 = 4KB
#define TILE_B (BN * BK)   // 4096 u16 = 8KB
// k-slot swizzle (verified R7: bank conflicts 2.1M -> 0): LDS slot (r,qs)
// holds global k-slot qs ^ ((r>>1)&3); applied on the global src (LDS dest
// stays linear for global_load_lds) and mirrored on the read.

// Stage a 64x32 u16 tile: 256 segments of 16B, one per thread.
__device__ __forceinline__ void stage_tileA(u16* lds, const u16* src, long long ld,
                                            int k0, int wave, int lane)
{
    const int segb = wave * 64;            // wave-uniform
    const int seg  = segb + lane;
    const int r  = seg >> 2;
    const int qs = seg & 3;
    const int qg = qs ^ ((r >> 1) & 3);
    gload16(lds + segb * 8, src + (long long)r * ld + k0 + qg * 8);
}

// Stage a 128x32 u16 tile: 512 segments of 16B, two per thread.
__device__ __forceinline__ void stage_tileB(u16* lds, const u16* src, long long ld,
                                            int k0, int wave, int lane)
{
#pragma unroll
    for (int i = 0; i < 2; ++i) {
        const int segb = wave * 64 + i * 256;   // wave-uniform
        const int seg  = segb + lane;
        const int r  = seg >> 2;
        const int qs = seg & 3;
        const int qg = qs ^ ((r >> 1) & 3);
        gload16(lds + segb * 8, src + (long long)r * ld + k0 + qg * 8);
    }
}

__device__ __forceinline__ bf16x8 frag(const u16* lds, int row, int quad) {
    const int slot = quad ^ ((row >> 1) & 3);  // matching read-side swizzle
    return __builtin_bit_cast(bf16x8, *(const u16x8*)(lds + row * BK + slot * 8));
}

// ---------- emulated-fp32 GEMM, 3 terms interleaved per K-tile ----------
// acc += Al*Bh + Ah*Bl + Ah*Bh per tile (per-element K-order identical to
// the verified R7 kernel). Double-buffered LDS, prefetch-before-compute,
// one barrier per K-tile. 64x128 tile, 4 waves (2Mx2N), acc[2][4].
template<bool SPLITOUT>
__global__ void gemm_cat3(const u16* __restrict__ Ah, const u16* __restrict__ Al,
                          const u16* __restrict__ Bh, const u16* __restrict__ Bl,
                          const float* __restrict__ bias,
                          void* __restrict__ C, u16* __restrict__ Cl,
                          int K, long long lda, long long ldb, long long ldc,
                          int xcx)
{
    __shared__ u16 Ahs[2][TILE_A];
    __shared__ u16 Als[2][TILE_A];
    __shared__ u16 Bhs[2][TILE_B];
    __shared__ u16 Bls[2][TILE_B];   // total 48KB -> 3 blocks/CU
    const int t = threadIdx.x;
    const int wave = t >> 6, lane = t & 63, quad = lane >> 4, l16 = lane & 15;
    const int waveM = (wave & 1) * 32, waveN = (wave >> 1) * 64;
    int bx, by;
    remap_xy(xcx, bx, by);
    const long long rowBase = (long long)by * BM;
    const long long colBase = (long long)bx * BN;
    Ah += rowBase * lda; Al += rowBase * lda;
    Bh += colBase * ldb; Bl += colBase * ldb;

    f32x4 acc[2][4];
#pragma unroll
    for (int i = 0; i < 2; ++i)
#pragma unroll
        for (int j = 0; j < 4; ++j) acc[i][j] = (f32x4){0.f, 0.f, 0.f, 0.f};

    auto stage4 = [&](int buf, int k0) {
        stage_tileA(Ahs[buf], Ah, lda, k0, wave, lane);
        stage_tileA(Als[buf], Al, lda, k0, wave, lane);
        stage_tileB(Bhs[buf], Bh, ldb, k0, wave, lane);
        stage_tileB(Bls[buf], Bl, ldb, k0, wave, lane);
    };

    stage4(0, 0);
    __syncthreads();
    int cur = 0;
    for (int k0 = 0; k0 < K; k0 += BK) {
        if (k0 + BK < K) stage4(cur ^ 1, k0 + BK);   // prefetch next tile

        bf16x8 ah[2], al[2], bh[4], bl[4];
#pragma unroll
        for (int mi = 0; mi < 2; ++mi) {
            int row = waveM + mi * 16 + l16;
            ah[mi] = frag(Ahs[cur], row, quad);
            al[mi] = frag(Als[cur], row, quad);
        }
#pragma unroll
        for (int ni = 0; ni < 4; ++ni) {
            int row = waveN + ni * 16 + l16;
            bh[ni] = frag(Bhs[cur], row, quad);
            bl[ni] = frag(Bls[cur], row, quad);
        }
#pragma unroll
        for (int mi = 0; mi < 2; ++mi)
#pragma unroll
            for (int ni = 0; ni < 4; ++ni) {
                acc[mi][ni] = __builtin_amdgcn_mfma_f32_16x16x32_bf16(al[mi], bh[ni], acc[mi][ni], 0, 0, 0);
                acc[mi][ni] = __builtin_amdgcn_mfma_f32_16x16x32_bf16(ah[mi], bl[ni], acc[mi][ni], 0, 0, 0);
                acc[mi][ni] = __builtin_amdgcn_mfma_f32_16x16x32_bf16(ah[mi], bh[ni], acc[mi][ni], 0, 0, 0);
            }

        __syncthreads();   // drains this iter's prefetch + barrier
        cur ^= 1;
    }

#pragma unroll
    for (int mi = 0; mi < 2; ++mi) {
#pragma unroll
        for (int ni = 0; ni < 4; ++ni) {
            long long col = colBase + waveN + ni * 16 + l16;
            float bv = bias ? bias[col] : 0.0f;
#pragma unroll
            for (int r = 0; r < 4; ++r) {
                long long row = rowBase + waveM + mi * 16 + quad * 4 + r;
                float f = acc[mi][ni][r] + bv;
                long long off = row * ldc + col;
                if (SPLITOUT) {
                    u16 h = f2bf(f);
                    ((u16*)C)[off] = h;
                    Cl[off] = f2bf(f - bf2f(h));
                } else {
                    ((float*)C)[off] = f;
                }
            }
        }
    }
}

// ---------- single-precision bf16 GEMM: C = A * B^T (+bias), dbuf ----------
template<bool OUTF32>
__global__ void gemm_bf(const u16* __restrict__ A, const u16* __restrict__ B,
                        const float* __restrict__ bias, void* __restrict__ C,
                        int K, long long lda, long long ldb, long long ldc,
                        int xcx)
{
    __shared__ u16 As[2][TILE_A];
    __shared__ u16 Bs[2][TILE_B];   // 24KB
    const int t = threadIdx.x;
    const int wave = t >> 6, lane = t & 63, quad = lane >> 4, l16 = lane & 15;
    const int waveM = (wave & 1) * 32, waveN = (wave >> 1) * 64;
    int bx, by;
    remap_xy(xcx, bx, by);
    const long long rowBase = (long long)by * BM;
    const long long colBase = (long long)bx * BN;
    A += rowBase * lda;
    B += colBase * ldb;

    f32x4 acc[2][4];
#pragma unroll
    for (int i = 0; i < 2; ++i)
#pragma unroll
        for (int j = 0; j < 4; ++j) acc[i][j] = (f32x4){0.f, 0.f, 0.f, 0.f};

    auto stage2 = [&](int buf, int k0) {
        stage_tileA(As[buf], A, lda, k0, wave, lane);
        stage_tileB(Bs[buf], B, ldb, k0, wave, lane);
    };

    stage2(0, 0);
    __syncthreads();
    int cur = 0;
    for (int k0 = 0; k0 < K; k0 += BK) {
        if (k0 + BK < K) stage2(cur ^ 1, k0 + BK);

        bf16x8 af[2], bfr[4];
#pragma unroll
        for (int mi = 0; mi < 2; ++mi) af[mi]  = frag(As[cur], waveM + mi * 16 + l16, quad);
#pragma unroll
        for (int ni = 0; ni < 4; ++ni) bfr[ni] = frag(Bs[cur], waveN + ni * 16 + l16, quad);
#pragma unroll
        for (int mi = 0; mi < 2; ++mi)
#pragma unroll
            for (int ni = 0; ni < 4; ++ni)
                acc[mi][ni] = __builtin_amdgcn_mfma_f32_16x16x32_bf16(af[mi], bfr[ni], acc[mi][ni], 0, 0, 0);

        __syncthreads();
        cur ^= 1;
    }

#pragma unroll
    for (int mi = 0; mi < 2; ++mi) {
#pragma unroll
        for (int ni = 0; ni < 4; ++ni) {
            long long col = colBase + waveN + ni * 16 + l16;
            float bv = bias ? bias[col] : 0.0f;
#pragma unroll
            for (int r = 0; r < 4; ++r) {
                long long row = rowBase + waveM + mi * 16 + quad * 4 + r;
                float f = acc[mi][ni][r] + bv;
                long long off = row * ldc + col;
                if (OUTF32) ((float*)C)[off] = f;
                else        ((u16*)C)[off] = f2bf(f);
            }
        }
    }
}

// ---------- PV GEMM, split-K z=4, NO atomics (R8) ----------
// Partials go to the DEAD upper 8KB of each Sc row-slot: PV reads bytes
// [0,8K) of a row (bf16 weights), writes fp32 partials to [8K,16K) —
// disjoint cache lines, no ordering needed. part = (float*)Sc, row stride
// 4096 floats; z-partial at [row*4096 + 2048 + z*512 + col].
__global__ void gemm_pv(const u16* __restrict__ A, const u16* __restrict__ B,
                        float* __restrict__ part, int KSEG,
                        long long lda, long long ldb)
{
    __shared__ u16 As[2][TILE_A];
    __shared__ u16 Bs[2][TILE_B];   // 24KB
    const int t = threadIdx.x;
    const int wave = t >> 6, lane = t & 63, quad = lane >> 4, l16 = lane & 15;
    const int waveM = (wave & 1) * 32, waveN = (wave >> 1) * 64;
    const long long rowBase = (long long)blockIdx.y * BM;
    const long long colBase = (long long)blockIdx.x * BN;
    const int bz = blockIdx.z;
    const int kbase = bz * KSEG;
    A += rowBase * lda;
    B += colBase * ldb;

    f32x4 acc[2][4];
#pragma unroll
    for (int i = 0; i < 2; ++i)
#pragma unroll
        for (int j = 0; j < 4; ++j) acc[i][j] = (f32x4){0.f, 0.f, 0.f, 0.f};

    auto stage2 = [&](int buf, int k0) {
        stage_tileA(As[buf], A, lda, k0, wave, lane);
        stage_tileB(Bs[buf], B, ldb, k0, wave, lane);
    };

    stage2(0, kbase);
    __syncthreads();
    int cur = 0;
    for (int k0 = kbase; k0 < kbase + KSEG; k0 += BK) {
        if (k0 + BK < kbase + KSEG) stage2(cur ^ 1, k0 + BK);

        bf16x8 af[2], bfr[4];
#pragma unroll
        for (int mi = 0; mi < 2; ++mi) af[mi]  = frag(As[cur], waveM + mi * 16 + l16, quad);
#pragma unroll
        for (int ni = 0; ni < 4; ++ni) bfr[ni] = frag(Bs[cur], waveN + ni * 16 + l16, quad);
#pragma unroll
        for (int mi = 0; mi < 2; ++mi)
#pragma unroll
            for (int ni = 0; ni < 4; ++ni)
                acc[mi][ni] = __builtin_amdgcn_mfma_f32_16x16x32_bf16(af[mi], bfr[ni], acc[mi][ni], 0, 0, 0);

        __syncthreads();
        cur ^= 1;
    }

#pragma unroll
    for (int mi = 0; mi < 2; ++mi) {
#pragma unroll
        for (int ni = 0; ni < 4; ++ni) {
            long long col = colBase + waveN + ni * 16 + l16;
#pragma unroll
            for (int r = 0; r < 4; ++r) {
                long long row = rowBase + waveM + mi * 16 + quad * 4 + r;
                part[row * 4096 + 2048 + bz * 512 + col] = acc[mi][ni][r];
            }
        }
    }
}

// Sum 4 z-partials per element, write bf16 Att. Grid 2048 x 128 threads.
__global__ void cvt_att(const float* __restrict__ Sc, u16* __restrict__ dst)
{
    const int row = blockIdx.x, t = threadIdx.x;
    const float* p = Sc + (long long)row * 4096 + 2048 + t * 4;
    float4 s0 = *(const float4*)(p);
    float4 s1 = *(const float4*)(p + 512);
    float4 s2 = *(const float4*)(p + 1024);
    float4 s3 = *(const float4*)(p + 1536);
    u16x4 v;
    v[0] = f2bf(s0.x + s1.x + s2.x + s3.x);
    v[1] = f2bf(s0.y + s1.y + s2.y + s3.y);
    v[2] = f2bf(s0.z + s1.z + s2.z + s3.z);
    v[3] = f2bf(s0.w + s1.w + s2.w + s3.w);
    *(u16x4*)(dst + (long long)row * 512 + t * 4) = v;
}

// ---------- fp32 -> bf16 hi/lo split, 8 elems/thread ----------
__global__ void split32(const float* __restrict__ src, u16* __restrict__ h,
                        u16* __restrict__ l, long long n)
{
    long long i = ((long long)blockIdx.x * blockDim.x + threadIdx.x) * 8;
    if (i >= n) return;
    float4 a = *(const float4*)(src + i);
    float4 b = *(const float4*)(src + i + 4);
    float v[8] = {a.x, a.y, a.z, a.w, b.x, b.y, b.z, b.w};
    u16x8 hv, lv;
#pragma unroll
    for (int j = 0; j < 8; ++j) {
        u16 hh = f2bf(v[j]);
        hv[j] = hh;
        lv[j] = f2bf(v[j] - bf2f(hh));
    }
    *(u16x8*)(h + i) = hv;
    *(u16x8*)(l + i) = lv;
}

// ---------- fp32 -> bf16 (hi only), 8 elems/thread ----------
__global__ void cvt32(const float* __restrict__ src, u16* __restrict__ dst, long long n)
{
    long long i = ((long long)blockIdx.x * blockDim.x + threadIdx.x) * 8;
    if (i >= n) return;
    float4 a = *(const float4*)(src + i);
    float4 b = *(const float4*)(src + i + 4);
    u16x8 v;
    v[0] = f2bf(a.x); v[1] = f2bf(a.y); v[2] = f2bf(a.z); v[3] = f2bf(a.w);
    v[4] = f2bf(b.x); v[5] = f2bf(b.y); v[6] = f2bf(b.z); v[7] = f2bf(b.w);
    *(u16x8*)(dst + i) = v;
}

// Fused per-batch memory prep: one pass over src [4096,512] fp32 ->
//   Mh/Ml [4096,512] bf16 hi/lo  +  MemT [512,4096] bf16 (transposed hi).
__global__ void prep_mem(const float* __restrict__ src, u16* __restrict__ h,
                         u16* __restrict__ l, u16* __restrict__ tdst)
{
    __shared__ u16 tile[64][72];
    const int dBase = blockIdx.x * 64, mBase = blockIdx.y * 64;
    const int t = threadIdx.x;
#pragma unroll
    for (int i = 0; i < 4; ++i) {
        int seg = t + i * 256;
        int r = seg >> 4;                 // m-local
        int c = (seg & 15) << 2;          // d-local
        long long off = (long long)(mBase + r) * 512 + dBase + c;
        float4 v = *(const float4*)(src + off);
        u16 h0 = f2bf(v.x), h1 = f2bf(v.y), h2 = f2bf(v.z), h3 = f2bf(v.w);
        tile[r][c] = h0; tile[r][c + 1] = h1; tile[r][c + 2] = h2; tile[r][c + 3] = h3;
        u16x4 hv; hv[0] = h0; hv[1] = h1; hv[2] = h2; hv[3] = h3;
        u16x4 lv;
        lv[0] = f2bf(v.x - bf2f(h0)); lv[1] = f2bf(v.y - bf2f(h1));
        lv[2] = f2bf(v.z - bf2f(h2)); lv[3] = f2bf(v.w - bf2f(h3));
        *(u16x4*)(h + off) = hv;
        *(u16x4*)(l + off) = lv;
    }
    __syncthreads();
#pragma unroll
    for (int i = 0; i < 2; ++i) {
        int seg = t + i * 256;
        int r = seg >> 3;          // d-local
        int c = (seg & 7) << 3;    // m-local
        u16x8 v;
#pragma unroll
        for (int j = 0; j < 8; ++j) v[j] = tile[c + j][r];
        *(u16x8*)(tdst + (long long)(dBase + r) * 4096 + mBase + c) = v;
    }
}

// One block per row of 4096 fp32 scores; writes normalized bf16 weights in
// place (first 8KB of the row's 16KB slot; row stride stays 8192 u16).
__global__ void softmax_rows(float* __restrict__ S)
{
    float* p = S + (long long)blockIdx.x * 4096;
    const int t = threadIdx.x;

    float4 v[4];
#pragma unroll
    for (int i = 0; i < 4; ++i) v[i] = ((const float4*)p)[t + i * 256];

    float m = -1e30f;
#pragma unroll
    for (int i = 0; i < 4; ++i)
        m = fmaxf(m, fmaxf(fmaxf(v[i].x, v[i].y), fmaxf(v[i].z, v[i].w)));
#pragma unroll
    for (int off = 32; off; off >>= 1) m = fmaxf(m, __shfl_xor(m, off));
    __shared__ float redm[4];
    if ((t & 63) == 0) redm[t >> 6] = m;
    __syncthreads();
    m = fmaxf(fmaxf(redm[0], redm[1]), fmaxf(redm[2], redm[3]));

    float s = 0.f;
#pragma unroll
    for (int i = 0; i < 4; ++i) {
        v[i].x = __expf(v[i].x - m); v[i].y = __expf(v[i].y - m);
        v[i].z = __expf(v[i].z - m); v[i].w = __expf(v[i].w - m);
        s += v[i].x + v[i].y + v[i].z + v[i].w;
    }
#pragma unroll
    for (int off = 32; off; off >>= 1) s += __shfl_xor(s, off);
    __shared__ float reds[4];
    if ((t & 63) == 0) reds[t >> 6] = s;
    __syncthreads();
    s = reds[0] + reds[1] + reds[2] + reds[3];
    const float inv = 1.0f / s;

    u16* pw = (u16*)p;
#pragma unroll
    for (int i = 0; i < 4; ++i) {
        u16x4 w;
        w[0] = f2bf(v[i].x * inv); w[1] = f2bf(v[i].y * inv);
        w[2] = f2bf(v[i].z * inv); w[3] = f2bf(v[i].w * inv);
        *(u16x4*)(pw + 4 * (t + i * 256)) = w;
    }
}

extern "C" void kernel_launch(void* const* d_in, const int* in_sizes, int n_in,
                              void* d_out, int out_size, void* d_ws, size_t ws_size,
                              hipStream_t stream)
{
    const float* x   = (const float*)d_in[0];   // [4,2048,1024] fp32
    const float* mem = (const float*)d_in[1];   // [4,4096,512]  fp32
    const float* Wq  = (const float*)d_in[2];   // [512,1024]    fp32
    const float* bq  = (const float*)d_in[3];   // [512]         fp32
    const float* Wm  = (const float*)d_in[4];   // [1024,512]    fp32
    const float* bm  = (const float*)d_in[5];   // [1024]        fp32

    // d_out (64MB) scratch schedule — every region dead before its final producer:
    //  [ 0, 8)  Qh  bf16 [8192,512]  (cvt_att overwrites batch rows with bf16 Att)
    //  [ 8,16)  Ql  bf16 [8192,512]
    //  [16,24)  Mh/Ml bf16 [4096,512] each (per batch)
    //  [24,28)  MemT bf16 [512,4096]
    //  [28,29)  Wqh, [29,30) Wql, [30,31) Wmh
    //  [32,64)  Xh/Xl (pre-loop) -> Sc fp32 [2048,4096] (in-loop; each row slot:
    //           [0,8K) bf16 weights, [8K,16K) fp32 PV z-partials) -> out1 (final)
    char* base = (char*)d_out;
    u16*   Qh   = (u16*)base;
    u16*   Ql   = (u16*)(base + (8ll  << 20));
    u16*   Mh   = (u16*)(base + (16ll << 20));
    u16*   Ml   = (u16*)(base + (20ll << 20));
    u16*   MemT = (u16*)(base + (24ll << 20));
    u16*   Wqh  = (u16*)(base + (28ll << 20));
    u16*   Wql  = (u16*)(base + (29ll << 20));
    u16*   Wmh  = (u16*)(base + (30ll << 20));
    u16*   Xh   = (u16*)(base + (32ll << 20));
    u16*   Xl   = (u16*)(base + (48ll << 20));
    float* Sc   = (float*)(base + (32ll << 20));
    float* out1 = (float*)d_out + 8388608ll;

    // one-time hi/lo splits (identical rounding to the verified in-GEMM split)
    split32<<<4096, 256, 0, stream>>>(x,  Xh,  Xl,  8192ll * 1024);
    split32<<<256,  256, 0, stream>>>(Wq, Wqh, Wql, 512ll * 1024);
    cvt32<<<256,    256, 0, stream>>>(Wm, Wmh,      1024ll * 512);

    // Qh/Ql = split(x @ Wq^T + bq)   [8192,512], K=1024
    // grid (4,128) = 512 blocks (was 256): 2 blocks/CU
    gemm_cat3<true><<<dim3(512 / BN, 8192 / BM), 256, 0, stream>>>(
        Xh, Xl, Wqh, Wql, bq, Qh, Ql, 1024, 1024, 1024, 512, 1);

    for (int b = 0; b < 4; ++b) {
        const float* Mb = mem + (long long)b * 4096 * 512;
        u16* Qhb = Qh + (long long)b * 2048 * 512;
        u16* Qlb = Ql + (long long)b * 2048 * 512;

        // fused split + transpose: one pass over Mb
        prep_mem<<<dim3(8, 64), 256, 0, stream>>>(Mb, Mh, Ml, MemT);

        // Sc = Qb @ Mb^T  [2048,4096], K=512
        // grid (32,32) = 1024 blocks (was 512): 3 blocks/CU (LDS 48KB)
        // xcx=4 -> each XCD 8x16 tiles = 2MB A + 2MB B in its L2
        gemm_cat3<false><<<dim3(4096 / BN, 2048 / BM), 256, 0, stream>>>(
            Qhb, Qlb, Mh, Ml, nullptr, Sc, nullptr, 512, 512, 512, 4096, 4);

        // softmax rows -> bf16 weights in place
        softmax_rows<<<dim3(2048), 256, 0, stream>>>(Sc);

        // PV partials (no atomics): grid (4,32,4), KSEG=1024
        gemm_pv<<<dim3(512 / BN, 2048 / BM, 4), 256, 0, stream>>>(
            (const u16*)Sc, MemT, Sc, 1024, 8192, 4096);

        // sum z-partials -> bf16 Att into dead Q rows (ldc=512 contiguous)
        cvt_att<<<dim3(2048), 128, 0, stream>>>(Sc, Qhb);
    }

    // out1 = Att @ Wm^T + bm   [8192,1024], K=512; grid (8,128) = 1024 blocks
    gemm_bf<true><<<dim3(1024 / BN, 8192 / BM), 256, 0, stream>>>(
        Qh, Wmh, bm, out1, 512, 512, 512, 1024, 1);

    // out0 = x (exact fp32 copy; overwrites dead scratch in [0,32MB)). Must be last.
    hipMemcpyAsync(d_out, x, 8192ll * 1024 * 4, hipMemcpyDeviceToDevice, stream);
}

// Round 10
// 476.386 us; speedup vs baseline: 1.1627x; 1.0732x over previous
//
#include <hip/hip_runtime.h>

typedef unsigned short u16;
typedef __bf16 bf16x8 __attribute__((ext_vector_type(8)));
typedef float f32x4 __attribute__((ext_vector_type(4)));
typedef unsigned short u16x8 __attribute__((ext_vector_type(8)));
typedef unsigned short u16x4 __attribute__((ext_vector_type(4)));

__device__ __forceinline__ u16 f2bf(float f) {
    unsigned u = __builtin_bit_cast(unsigned, f);
    u += 0x7FFFu + ((u >> 16) & 1u);   // RNE
    return (u16)(u >> 16);
}
__device__ __forceinline__ float bf2f(u16 s) {
    return __builtin_bit_cast(float, ((unsigned)s) << 16);
}

// async 16B global->LDS. LDS dest = wave-uniform base + lane*16B (m97/m104).
__device__ __forceinline__ void gload16(u16* lds, const u16* g) {
    __builtin_amdgcn_global_load_lds(
        (__attribute__((address_space(1))) unsigned*)g,
        (__attribute__((address_space(3))) unsigned*)lds,
        16, 0, 0);
}

// XCD-chunked tile remap (T1): dispatch id d -> XCD d&7; each XCD owns a
// cw x ch tile sub-rectangle (verified R7: FETCH 66->25MB).
__device__ __forceinline__ void remap_xy(int xcx, int& bx, int& by) {
    const int nx = gridDim.x;
    const int d = blockIdx.y * nx + blockIdx.x;
    const int xcd = d & 7, i = d >> 3;
    const int xcy = 8 / xcx;
    const int cw = nx / xcx;
    const int ch = (int)gridDim.y / xcy;
    bx = (xcd % xcx) * cw + i % cw;
    by = (xcd / xcx) * ch + i / cw;
}

// R10: BM back to 128 (R9 measured BM=64 as -9% on cat3: staging traffic
// x1.5, occupancy gain useless because the vmcnt(0) drain was the cost).
// The drain itself is removed this round via counted-vmcnt barriers (T4).
#define BM 128
#define BN 128
#define BK 32
#define TILE (BM * BK)   // 4096 u16 = 8KB per 128x32 tile
// k-slot swizzle (verified R7: bank conflicts 2.1M -> 0): LDS slot (r,qs)
// holds global k-slot qs ^ ((r>>1)&3); applied on the global src (LDS dest
// stays linear for global_load_lds) and mirrored on the read.

// Stage a 128x32 u16 tile: 512 segments of 16B, two gload16 per thread.
__device__ __forceinline__ void stage_tile(u16* lds, const u16* src, long long ld,
                                           int k0, int wave, int lane)
{
#pragma unroll
    for (int i = 0; i < 2; ++i) {
        const int segb = wave * 64 + i * 256;   // wave-uniform
        const int seg  = segb + lane;
        const int r  = seg >> 2;
        const int qs = seg & 3;
        const int qg = qs ^ ((r >> 1) & 3);
        gload16(lds + segb * 8, src + (long long)r * ld + k0 + qg * 8);
    }
}

__device__ __forceinline__ bf16x8 frag(const u16* lds, int row, int quad) {
    const int slot = quad ^ ((row >> 1) & 3);  // matching read-side swizzle
    return __builtin_bit_cast(bf16x8, *(const u16x8*)(lds + row * BK + slot * 8));
}

// Counted-vmcnt barrier pair (T4): after issuing this iteration's N loads,
// wait for the PREVIOUS iteration's N (vmcnt(N) leaves the new N in flight),
// then barrier. Single asm blocks with "memory" clobber so no LDS access can
// slide between the wait and the barrier.
#define WAIT8_BARRIER()  asm volatile("s_waitcnt vmcnt(8)\n\ts_barrier" ::: "memory")
#define WAIT4_BARRIER()  asm volatile("s_waitcnt vmcnt(4)\n\ts_barrier" ::: "memory")
#define WAIT0_BARRIER()  asm volatile("s_waitcnt vmcnt(0)\n\ts_barrier" ::: "memory")
#define BARRIER()        asm volatile("s_barrier" ::: "memory")

// ---------- emulated-fp32 GEMM, 3 terms interleaved per K-tile ----------
// acc += Al*Bh + Ah*Bl + Ah*Bh per tile (per-element K-order identical to
// the verified R7 kernel). Double-buffered LDS, prefetch-before-compute,
// counted-vmcnt barriers: loads stay in flight across the barrier; their
// latency is hidden under the previous tile's 48 MFMAs.
template<bool SPLITOUT>
__global__ void gemm_cat3(const u16* __restrict__ Ah, const u16* __restrict__ Al,
                          const u16* __restrict__ Bh, const u16* __restrict__ Bl,
                          const float* __restrict__ bias,
                          void* __restrict__ C, u16* __restrict__ Cl,
                          int K, long long lda, long long ldb, long long ldc,
                          int xcx)
{
    __shared__ u16 sm[2][4][TILE];   // 64KB: {Ah,Al,Bh,Bl} x dbuf
    const int t = threadIdx.x;
    const int wave = t >> 6, lane = t & 63, quad = lane >> 4, l16 = lane & 15;
    const int waveM = (wave & 1) * 64, waveN = (wave >> 1) * 64;
    int bx, by;
    remap_xy(xcx, bx, by);
    const long long rowBase = (long long)by * BM;
    const long long colBase = (long long)bx * BN;
    Ah += rowBase * lda; Al += rowBase * lda;
    Bh += colBase * ldb; Bl += colBase * ldb;

    f32x4 acc[4][4];
#pragma unroll
    for (int i = 0; i < 4; ++i)
#pragma unroll
        for (int j = 0; j < 4; ++j) acc[i][j] = (f32x4){0.f, 0.f, 0.f, 0.f};

    auto stage4 = [&](int buf, int k0) {   // 8 gload16 per thread
        stage_tile(sm[buf][0], Ah, lda, k0, wave, lane);
        stage_tile(sm[buf][1], Al, lda, k0, wave, lane);
        stage_tile(sm[buf][2], Bh, ldb, k0, wave, lane);
        stage_tile(sm[buf][3], Bl, ldb, k0, wave, lane);
    };

    stage4(0, 0);
    int cur = 0;
    for (int k0 = 0; k0 < K; k0 += BK) {
        if (k0 + BK < K) {
            stage4(cur ^ 1, k0 + BK);   // prefetch next tile (+8 in flight)
            WAIT8_BARRIER();            // previous 8 (buf[cur]) landed, all waves
        } else {
            WAIT0_BARRIER();            // last tile: drain
        }

        bf16x8 ah[4], al[4], bh[4], bl[4];
#pragma unroll
        for (int mi = 0; mi < 4; ++mi) {
            int row = waveM + mi * 16 + l16;
            ah[mi] = frag(sm[cur][0], row, quad);
            al[mi] = frag(sm[cur][1], row, quad);
        }
#pragma unroll
        for (int ni = 0; ni < 4; ++ni) {
            int row = waveN + ni * 16 + l16;
            bh[ni] = frag(sm[cur][2], row, quad);
            bl[ni] = frag(sm[cur][3], row, quad);
        }
#pragma unroll
        for (int mi = 0; mi < 4; ++mi)
#pragma unroll
            for (int ni = 0; ni < 4; ++ni) {
                acc[mi][ni] = __builtin_amdgcn_mfma_f32_16x16x32_bf16(al[mi], bh[ni], acc[mi][ni], 0, 0, 0);
                acc[mi][ni] = __builtin_amdgcn_mfma_f32_16x16x32_bf16(ah[mi], bl[ni], acc[mi][ni], 0, 0, 0);
                acc[mi][ni] = __builtin_amdgcn_mfma_f32_16x16x32_bf16(ah[mi], bh[ni], acc[mi][ni], 0, 0, 0);
            }

        BARRIER();   // all waves done reading buf[cur] (ds_reads consumed by
                     // MFMAs above => complete); next iter may overwrite it
        cur ^= 1;
    }

#pragma unroll
    for (int mi = 0; mi < 4; ++mi) {
#pragma unroll
        for (int ni = 0; ni < 4; ++ni) {
            long long col = colBase + waveN + ni * 16 + l16;
            float bv = bias ? bias[col] : 0.0f;
#pragma unroll
            for (int r = 0; r < 4; ++r) {
                long long row = rowBase + waveM + mi * 16 + quad * 4 + r;
                float f = acc[mi][ni][r] + bv;
                long long off = row * ldc + col;
                if (SPLITOUT) {
                    u16 h = f2bf(f);
                    ((u16*)C)[off] = h;
                    Cl[off] = f2bf(f - bf2f(h));
                } else {
                    ((float*)C)[off] = f;
                }
            }
        }
    }
}

// ---------- single-precision bf16 GEMM: C = A * B^T (+bias) ----------
template<bool OUTF32>
__global__ void gemm_bf(const u16* __restrict__ A, const u16* __restrict__ B,
                        const float* __restrict__ bias, void* __restrict__ C,
                        int K, long long lda, long long ldb, long long ldc,
                        int xcx)
{
    __shared__ u16 sm[2][2][TILE];   // 32KB
    const int t = threadIdx.x;
    const int wave = t >> 6, lane = t & 63, quad = lane >> 4, l16 = lane & 15;
    const int waveM = (wave & 1) * 64, waveN = (wave >> 1) * 64;
    int bx, by;
    remap_xy(xcx, bx, by);
    const long long rowBase = (long long)by * BM;
    const long long colBase = (long long)bx * BN;
    A += rowBase * lda;
    B += colBase * ldb;

    f32x4 acc[4][4];
#pragma unroll
    for (int i = 0; i < 4; ++i)
#pragma unroll
        for (int j = 0; j < 4; ++j) acc[i][j] = (f32x4){0.f, 0.f, 0.f, 0.f};

    auto stage2 = [&](int buf, int k0) {   // 4 gload16 per thread
        stage_tile(sm[buf][0], A, lda, k0, wave, lane);
        stage_tile(sm[buf][1], B, ldb, k0, wave, lane);
    };

    stage2(0, 0);
    int cur = 0;
    for (int k0 = 0; k0 < K; k0 += BK) {
        if (k0 + BK < K) {
            stage2(cur ^ 1, k0 + BK);
            WAIT4_BARRIER();
        } else {
            WAIT0_BARRIER();
        }

        bf16x8 af[4], bfr[4];
#pragma unroll
        for (int mi = 0; mi < 4; ++mi) af[mi]  = frag(sm[cur][0], waveM + mi * 16 + l16, quad);
#pragma unroll
        for (int ni = 0; ni < 4; ++ni) bfr[ni] = frag(sm[cur][1], waveN + ni * 16 + l16, quad);
#pragma unroll
        for (int mi = 0; mi < 4; ++mi)
#pragma unroll
            for (int ni = 0; ni < 4; ++ni)
                acc[mi][ni] = __builtin_amdgcn_mfma_f32_16x16x32_bf16(af[mi], bfr[ni], acc[mi][ni], 0, 0, 0);

        BARRIER();
        cur ^= 1;
    }

#pragma unroll
    for (int mi = 0; mi < 4; ++mi) {
#pragma unroll
        for (int ni = 0; ni < 4; ++ni) {
            long long col = colBase + waveN + ni * 16 + l16;
            float bv = bias ? bias[col] : 0.0f;
#pragma unroll
            for (int r = 0; r < 4; ++r) {
                long long row = rowBase + waveM + mi * 16 + quad * 4 + r;
                float f = acc[mi][ni][r] + bv;
                long long off = row * ldc + col;
                if (OUTF32) ((float*)C)[off] = f;
                else        ((u16*)C)[off] = f2bf(f);
            }
        }
    }
}

// ---------- PV GEMM, split-K z=4, NO atomics (verified R9) ----------
// Partials go to the DEAD upper 8KB of each Sc row-slot: PV reads bytes
// [0,8K) of a row (bf16 weights), writes fp32 partials to [8K,16K) —
// disjoint lines, no ordering needed. part stride 4096 floats;
// z-partial at [row*4096 + 2048 + z*512 + col].
__global__ void gemm_pv(const u16* __restrict__ A, const u16* __restrict__ B,
                        float* __restrict__ part, int KSEG,
                        long long lda, long long ldb)
{
    __shared__ u16 sm[2][2][TILE];   // 32KB
    const int t = threadIdx.x;
    const int wave = t >> 6, lane = t & 63, quad = lane >> 4, l16 = lane & 15;
    const int waveM = (wave & 1) * 64, waveN = (wave >> 1) * 64;
    const long long rowBase = (long long)blockIdx.y * BM;
    const long long colBase = (long long)blockIdx.x * BN;
    const int bz = blockIdx.z;
    const int kbase = bz * KSEG;
    A += rowBase * lda;
    B += colBase * ldb;

    f32x4 acc[4][4];
#pragma unroll
    for (int i = 0; i < 4; ++i)
#pragma unroll
        for (int j = 0; j < 4; ++j) acc[i][j] = (f32x4){0.f, 0.f, 0.f, 0.f};

    auto stage2 = [&](int buf, int k0) {
        stage_tile(sm[buf][0], A, lda, k0, wave, lane);
        stage_tile(sm[buf][1], B, ldb, k0, wave, lane);
    };

    stage2(0, kbase);
    int cur = 0;
    for (int k0 = kbase; k0 < kbase + KSEG; k0 += BK) {
        if (k0 + BK < kbase + KSEG) {
            stage2(cur ^ 1, k0 + BK);
            WAIT4_BARRIER();
        } else {
            WAIT0_BARRIER();
        }

        bf16x8 af[4], bfr[4];
#pragma unroll
        for (int mi = 0; mi < 4; ++mi) af[mi]  = frag(sm[cur][0], waveM + mi * 16 + l16, quad);
#pragma unroll
        for (int ni = 0; ni < 4; ++ni) bfr[ni] = frag(sm[cur][1], waveN + ni * 16 + l16, quad);
#pragma unroll
        for (int mi = 0; mi < 4; ++mi)
#pragma unroll
            for (int ni = 0; ni < 4; ++ni)
                acc[mi][ni] = __builtin_amdgcn_mfma_f32_16x16x32_bf16(af[mi], bfr[ni], acc[mi][ni], 0, 0, 0);

        BARRIER();
        cur ^= 1;
    }

#pragma unroll
    for (int mi = 0; mi < 4; ++mi) {
#pragma unroll
        for (int ni = 0; ni < 4; ++ni) {
            long long col = colBase + waveN + ni * 16 + l16;
#pragma unroll
            for (int r = 0; r < 4; ++r) {
                long long row = rowBase + waveM + mi * 16 + quad * 4 + r;
                part[row * 4096 + 2048 + bz * 512 + col] = acc[mi][ni][r];
            }
        }
    }
}

// Sum 4 z-partials per element, write bf16 Att. Grid 2048 x 128 threads.
__global__ void cvt_att(const float* __restrict__ Sc, u16* __restrict__ dst)
{
    const int row = blockIdx.x, t = threadIdx.x;
    const float* p = Sc + (long long)row * 4096 + 2048 + t * 4;
    float4 s0 = *(const float4*)(p);
    float4 s1 = *(const float4*)(p + 512);
    float4 s2 = *(const float4*)(p + 1024);
    float4 s3 = *(const float4*)(p + 1536);
    u16x4 v;
    v[0] = f2bf(s0.x + s1.x + s2.x + s3.x);
    v[1] = f2bf(s0.y + s1.y + s2.y + s3.y);
    v[2] = f2bf(s0.z + s1.z + s2.z + s3.z);
    v[3] = f2bf(s0.w + s1.w + s2.w + s3.w);
    *(u16x4*)(dst + (long long)row * 512 + t * 4) = v;
}

// ---------- fp32 -> bf16 hi/lo split, 8 elems/thread ----------
__global__ void split32(const float* __restrict__ src, u16* __restrict__ h,
                        u16* __restrict__ l, long long n)
{
    long long i = ((long long)blockIdx.x * blockDim.x + threadIdx.x) * 8;
    if (i >= n) return;
    float4 a = *(const float4*)(src + i);
    float4 b = *(const float4*)(src + i + 4);
    float v[8] = {a.x, a.y, a.z, a.w, b.x, b.y, b.z, b.w};
    u16x8 hv, lv;
#pragma unroll
    for (int j = 0; j < 8; ++j) {
        u16 hh = f2bf(v[j]);
        hv[j] = hh;
        lv[j] = f2bf(v[j] - bf2f(hh));
    }
    *(u16x8*)(h + i) = hv;
    *(u16x8*)(l + i) = lv;
}

// ---------- fp32 -> bf16 (hi only), 8 elems/thread ----------
__global__ void cvt32(const float* __restrict__ src, u16* __restrict__ dst, long long n)
{
    long long i = ((long long)blockIdx.x * blockDim.x + threadIdx.x) * 8;
    if (i >= n) return;
    float4 a = *(const float4*)(src + i);
    float4 b = *(const float4*)(src + i + 4);
    u16x8 v;
    v[0] = f2bf(a.x); v[1] = f2bf(a.y); v[2] = f2bf(a.z); v[3] = f2bf(a.w);
    v[4] = f2bf(b.x); v[5] = f2bf(b.y); v[6] = f2bf(b.z); v[7] = f2bf(b.w);
    *(u16x8*)(dst + i) = v;
}

// Fused per-batch memory prep: one pass over src [4096,512] fp32 ->
//   Mh/Ml [4096,512] bf16 hi/lo  +  MemT [512,4096] bf16 (transposed hi).
__global__ void prep_mem(const float* __restrict__ src, u16* __restrict__ h,
                         u16* __restrict__ l, u16* __restrict__ tdst)
{
    __shared__ u16 tile[64][72];
    const int dBase = blockIdx.x * 64, mBase = blockIdx.y * 64;
    const int t = threadIdx.x;
#pragma unroll
    for (int i = 0; i < 4; ++i) {
        int seg = t + i * 256;
        int r = seg >> 4;                 // m-local
        int c = (seg & 15) << 2;          // d-local
        long long off = (long long)(mBase + r) * 512 + dBase + c;
        float4 v = *(const float4*)(src + off);
        u16 h0 = f2bf(v.x), h1 = f2bf(v.y), h2 = f2bf(v.z), h3 = f2bf(v.w);
        tile[r][c] = h0; tile[r][c + 1] = h1; tile[r][c + 2] = h2; tile[r][c + 3] = h3;
        u16x4 hv; hv[0] = h0; hv[1] = h1; hv[2] = h2; hv[3] = h3;
        u16x4 lv;
        lv[0] = f2bf(v.x - bf2f(h0)); lv[1] = f2bf(v.y - bf2f(h1));
        lv[2] = f2bf(v.z - bf2f(h2)); lv[3] = f2bf(v.w - bf2f(h3));
        *(u16x4*)(h + off) = hv;
        *(u16x4*)(l + off) = lv;
    }
    __syncthreads();
#pragma unroll
    for (int i = 0; i < 2; ++i) {
        int seg = t + i * 256;
        int r = seg >> 3;          // d-local
        int c = (seg & 7) << 3;    // m-local
        u16x8 v;
#pragma unroll
        for (int j = 0; j < 8; ++j) v[j] = tile[c + j][r];
        *(u16x8*)(tdst + (long long)(dBase + r) * 4096 + mBase + c) = v;
    }
}

// One block per row of 4096 fp32 scores; writes normalized bf16 weights in
// place (first 8KB of the row's 16KB slot; row stride stays 8192 u16).
__global__ void softmax_rows(float* __restrict__ S)
{
    float* p = S + (long long)blockIdx.x * 4096;
    const int t = threadIdx.x;

    float4 v[4];
#pragma unroll
    for (int i = 0; i < 4; ++i) v[i] = ((const float4*)p)[t + i * 256];

    float m = -1e30f;
#pragma unroll
    for (int i = 0; i < 4; ++i)
        m = fmaxf(m, fmaxf(fmaxf(v[i].x, v[i].y), fmaxf(v[i].z, v[i].w)));
#pragma unroll
    for (int off = 32; off; off >>= 1) m = fmaxf(m, __shfl_xor(m, off));
    __shared__ float redm[4];
    if ((t & 63) == 0) redm[t >> 6] = m;
    __syncthreads();
    m = fmaxf(fmaxf(redm[0], redm[1]), fmaxf(redm[2], redm[3]));

    float s = 0.f;
#pragma unroll
    for (int i = 0; i < 4; ++i) {
        v[i].x = __expf(v[i].x - m); v[i].y = __expf(v[i].y - m);
        v[i].z = __expf(v[i].z - m); v[i].w = __expf(v[i].w - m);
        s += v[i].x + v[i].y + v[i].z + v[i].w;
    }
#pragma unroll
    for (int off = 32; off; off >>= 1) s += __shfl_xor(s, off);
    __shared__ float reds[4];
    if ((t & 63) == 0) reds[t >> 6] = s;
    __syncthreads();
    s = reds[0] + reds[1] + reds[2] + reds[3];
    const float inv = 1.0f / s;

    u16* pw = (u16*)p;
#pragma unroll
    for (int i = 0; i < 4; ++i) {
        u16x4 w;
        w[0] = f2bf(v[i].x * inv); w[1] = f2bf(v[i].y * inv);
        w[2] = f2bf(v[i].z * inv); w[3] = f2bf(v[i].w * inv);
        *(u16x4*)(pw + 4 * (t + i * 256)) = w;
    }
}

extern "C" void kernel_launch(void* const* d_in, const int* in_sizes, int n_in,
                              void* d_out, int out_size, void* d_ws, size_t ws_size,
                              hipStream_t stream)
{
    const float* x   = (const float*)d_in[0];   // [4,2048,1024] fp32
    const float* mem = (const float*)d_in[1];   // [4,4096,512]  fp32
    const float* Wq  = (const float*)d_in[2];   // [512,1024]    fp32
    const float* bq  = (const float*)d_in[3];   // [512]         fp32
    const float* Wm  = (const float*)d_in[4];   // [1024,512]    fp32
    const float* bm  = (const float*)d_in[5];   // [1024]        fp32

    // d_out (64MB) scratch schedule — every region dead before its final producer:
    //  [ 0, 8)  Qh  bf16 [8192,512]  (cvt_att overwrites batch rows with bf16 Att)
    //  [ 8,16)  Ql  bf16 [8192,512]
    //  [16,24)  Mh/Ml bf16 [4096,512] each (per batch)
    //  [24,28)  MemT bf16 [512,4096]
    //  [28,29)  Wqh, [29,30) Wql, [30,31) Wmh
    //  [32,64)  Xh/Xl (pre-loop) -> Sc fp32 [2048,4096] (in-loop; each row slot:
    //           [0,8K) bf16 weights, [8K,16K) fp32 PV z-partials) -> out1 (final)
    char* base = (char*)d_out;
    u16*   Qh   = (u16*)base;
    u16*   Ql   = (u16*)(base + (8ll  << 20));
    u16*   Mh   = (u16*)(base + (16ll << 20));
    u16*   Ml   = (u16*)(base + (20ll << 20));
    u16*   MemT = (u16*)(base + (24ll << 20));
    u16*   Wqh  = (u16*)(base + (28ll << 20));
    u16*   Wql  = (u16*)(base + (29ll << 20));
    u16*   Wmh  = (u16*)(base + (30ll << 20));
    u16*   Xh   = (u16*)(base + (32ll << 20));
    u16*   Xl   = (u16*)(base + (48ll << 20));
    float* Sc   = (float*)(base + (32ll << 20));
    float* out1 = (float*)d_out + 8388608ll;

    // one-time hi/lo splits (identical rounding to the verified in-GEMM split)
    split32<<<4096, 256, 0, stream>>>(x,  Xh,  Xl,  8192ll * 1024);
    split32<<<256,  256, 0, stream>>>(Wq, Wqh, Wql, 512ll * 1024);
    cvt32<<<256,    256, 0, stream>>>(Wm, Wmh,      1024ll * 512);

    // Qh/Ql = split(x @ Wq^T + bq)   [8192,512], K=1024; grid (4,64)
    gemm_cat3<true><<<dim3(512 / BN, 8192 / BM), 256, 0, stream>>>(
        Xh, Xl, Wqh, Wql, bq, Qh, Ql, 1024, 1024, 1024, 512, 1);

    for (int b = 0; b < 4; ++b) {
        const float* Mb = mem + (long long)b * 4096 * 512;
        u16* Qhb = Qh + (long long)b * 2048 * 512;
        u16* Qlb = Ql + (long long)b * 2048 * 512;

        // fused split + transpose: one pass over Mb
        prep_mem<<<dim3(8, 64), 256, 0, stream>>>(Mb, Mh, Ml, MemT);

        // Sc = Qb @ Mb^T  [2048,4096], K=512; grid (32,16), xcx=4:
        // each XCD an 8x8 tile square (2MB A + 2MB B in its L2)
        gemm_cat3<false><<<dim3(4096 / BN, 2048 / BM), 256, 0, stream>>>(
            Qhb, Qlb, Mh, Ml, nullptr, Sc, nullptr, 512, 512, 512, 4096, 4);

        // softmax rows -> bf16 weights in place
        softmax_rows<<<dim3(2048), 256, 0, stream>>>(Sc);

        // PV partials (no atomics): grid (4,16,4), KSEG=1024
        gemm_pv<<<dim3(512 / BN, 2048 / BM, 4), 256, 0, stream>>>(
            (const u16*)Sc, MemT, Sc, 1024, 8192, 4096);

        // sum z-partials -> bf16 Att into dead Q rows (ldc=512 contiguous)
        cvt_att<<<dim3(2048), 128, 0, stream>>>(Sc, Qhb);
    }

    // out1 = Att @ Wm^T + bm   [8192,1024], K=512; grid (8,64)
    gemm_bf<true><<<dim3(1024 / BN, 8192 / BM), 256, 0, stream>>>(
        Qh, Wmh, bm, out1, 512, 512, 512, 1024, 1);

    // out0 = x (exact fp32 copy; overwrites dead scratch in [0,32MB)). Must be last.
    hipMemcpyAsync(d_out, x, 8192ll * 1024 * 4, hipMemcpyDeviceToDevice, stream);
}

// Round 11
// 451.375 us; speedup vs baseline: 1.2271x; 1.0554x over previous
//
#include <hip/hip_runtime.h>

typedef unsigned short u16;
typedef __bf16 bf16x8 __attribute__((ext_vector_type(8)));
typedef float f32x4 __attribute__((ext_vector_type(4)));
typedef unsigned short u16x8 __attribute__((ext_vector_type(8)));
typedef unsigned short u16x4 __attribute__((ext_vector_type(4)));

__device__ __forceinline__ u16 f2bf(float f) {
    unsigned u = __builtin_bit_cast(unsigned, f);
    u += 0x7FFFu + ((u >> 16) & 1u);   // RNE
    return (u16)(u >> 16);
}
__device__ __forceinline__ float bf2f(u16 s) {
    return __builtin_bit_cast(float, ((unsigned)s) << 16);
}

// async 16B global->LDS. LDS dest = wave-uniform base + lane*16B (m97/m104).
__device__ __forceinline__ void gload16(u16* lds, const u16* g) {
    __builtin_amdgcn_global_load_lds(
        (__attribute__((address_space(1))) unsigned*)g,
        (__attribute__((address_space(3))) unsigned*)lds,
        16, 0, 0);
}

// XCD-chunked tile remap (T1): dispatch id d -> XCD d&7 (verified R7:
// FETCH 66->25MB).
__device__ __forceinline__ void remap_xy(int xcx, int& bx, int& by) {
    const int nx = gridDim.x;
    const int d = blockIdx.y * nx + blockIdx.x;
    const int xcd = d & 7, i = d >> 3;
    const int xcy = 8 / xcx;
    const int cw = nx / xcx;
    const int ch = (int)gridDim.y / xcy;
    bx = (xcd % xcx) * cw + i % cw;
    by = (xcd / xcx) * ch + i / cw;
}

#define BM 128
#define BN 128
#define BK 32
#define TILE (BM * BK)    // 8KB tile for BK=32 path (cat3)
#define BK2 64
#define TILE2 (BM * BK2)  // 16KB tile for BK=64 path (bf/pv) — R11: full
                          // 128B-line row reads on strided A/B (PV was
                          // ~50% line-efficiency fetch-bound at BK=32)

// ---- BK=32 staging/frag (cat3; verified R7-R10: 0 bank conflicts) ----
__device__ __forceinline__ void stage_tile(u16* lds, const u16* src, long long ld,
                                           int k0, int wave, int lane)
{
#pragma unroll
    for (int i = 0; i < 2; ++i) {
        const int segb = wave * 64 + i * 256;   // wave-uniform
        const int seg  = segb + lane;
        const int r  = seg >> 2;
        const int qs = seg & 3;
        const int qg = qs ^ ((r >> 1) & 3);     // pre-swizzled global k-slot
        gload16(lds + segb * 8, src + (long long)r * ld + k0 + qg * 8);
    }
}
__device__ __forceinline__ bf16x8 frag(const u16* lds, int row, int quad) {
    const int slot = quad ^ ((row >> 1) & 3);
    return __builtin_bit_cast(bf16x8, *(const u16x8*)(lds + row * BK + slot * 8));
}

// ---- BK=64 staging/frag (bf/pv) — 8 16B-slots/row, slot ^= row&7 swizzle
// (both-sides involution; 16 rows x 4 quads -> uniform 8 accesses/bank) ----
__device__ __forceinline__ void stage_tile64(u16* lds, const u16* src, long long ld,
                                             int k0, int wave, int lane)
{
#pragma unroll
    for (int i = 0; i < 4; ++i) {
        const int segb = wave * 64 + i * 256;   // wave-uniform
        const int seg  = segb + lane;
        const int r  = seg >> 3;
        const int qs = seg & 7;
        const int qg = qs ^ (r & 7);            // pre-swizzled global k-slot
        gload16(lds + segb * 8, src + (long long)r * ld + k0 + qg * 8);
    }
}
__device__ __forceinline__ bf16x8 frag64(const u16* lds, int row, int quad, int kw) {
    const int slot = (kw * 4 + quad) ^ (row & 7);
    return __builtin_bit_cast(bf16x8, *(const u16x8*)(lds + row * BK2 + slot * 8));
}

// Counted-vmcnt barrier pair (T4, verified R10: -35us): wait for the
// PREVIOUS iteration's loads only; this iteration's stay in flight.
#define WAIT8_BARRIER()  asm volatile("s_waitcnt vmcnt(8)\n\ts_barrier" ::: "memory")
#define WAIT0_BARRIER()  asm volatile("s_waitcnt vmcnt(0)\n\ts_barrier" ::: "memory")
#define BARRIER()        asm volatile("s_barrier" ::: "memory")

// ---------- emulated-fp32 GEMM, 3 terms interleaved per K-tile ----------
// UNCHANGED from R10 (BK=64 here would cut occupancy 2->1 blocks/CU — the
// m132 regression pattern). acc += Al*Bh + Ah*Bl + Ah*Bh per tile.
template<bool SPLITOUT>
__global__ void gemm_cat3(const u16* __restrict__ Ah, const u16* __restrict__ Al,
                          const u16* __restrict__ Bh, const u16* __restrict__ Bl,
                          const float* __restrict__ bias,
                          void* __restrict__ C, u16* __restrict__ Cl,
                          int K, long long lda, long long ldb, long long ldc,
                          int xcx)
{
    __shared__ u16 sm[2][4][TILE];   // 64KB
    const int t = threadIdx.x;
    const int wave = t >> 6, lane = t & 63, quad = lane >> 4, l16 = lane & 15;
    const int waveM = (wave & 1) * 64, waveN = (wave >> 1) * 64;
    int bx, by;
    remap_xy(xcx, bx, by);
    const long long rowBase = (long long)by * BM;
    const long long colBase = (long long)bx * BN;
    Ah += rowBase * lda; Al += rowBase * lda;
    Bh += colBase * ldb; Bl += colBase * ldb;

    f32x4 acc[4][4];
#pragma unroll
    for (int i = 0; i < 4; ++i)
#pragma unroll
        for (int j = 0; j < 4; ++j) acc[i][j] = (f32x4){0.f, 0.f, 0.f, 0.f};

    auto stage4 = [&](int buf, int k0) {   // 8 gload16 per thread
        stage_tile(sm[buf][0], Ah, lda, k0, wave, lane);
        stage_tile(sm[buf][1], Al, lda, k0, wave, lane);
        stage_tile(sm[buf][2], Bh, ldb, k0, wave, lane);
        stage_tile(sm[buf][3], Bl, ldb, k0, wave, lane);
    };

    stage4(0, 0);
    int cur = 0;
    for (int k0 = 0; k0 < K; k0 += BK) {
        if (k0 + BK < K) {
            stage4(cur ^ 1, k0 + BK);
            WAIT8_BARRIER();
        } else {
            WAIT0_BARRIER();
        }

        bf16x8 ah[4], al[4], bh[4], bl[4];
#pragma unroll
        for (int mi = 0; mi < 4; ++mi) {
            int row = waveM + mi * 16 + l16;
            ah[mi] = frag(sm[cur][0], row, quad);
            al[mi] = frag(sm[cur][1], row, quad);
        }
#pragma unroll
        for (int ni = 0; ni < 4; ++ni) {
            int row = waveN + ni * 16 + l16;
            bh[ni] = frag(sm[cur][2], row, quad);
            bl[ni] = frag(sm[cur][3], row, quad);
        }
#pragma unroll
        for (int mi = 0; mi < 4; ++mi)
#pragma unroll
            for (int ni = 0; ni < 4; ++ni) {
                acc[mi][ni] = __builtin_amdgcn_mfma_f32_16x16x32_bf16(al[mi], bh[ni], acc[mi][ni], 0, 0, 0);
                acc[mi][ni] = __builtin_amdgcn_mfma_f32_16x16x32_bf16(ah[mi], bl[ni], acc[mi][ni], 0, 0, 0);
                acc[mi][ni] = __builtin_amdgcn_mfma_f32_16x16x32_bf16(ah[mi], bh[ni], acc[mi][ni], 0, 0, 0);
            }

        BARRIER();
        cur ^= 1;
    }

#pragma unroll
    for (int mi = 0; mi < 4; ++mi) {
#pragma unroll
        for (int ni = 0; ni < 4; ++ni) {
            long long col = colBase + waveN + ni * 16 + l16;
            float bv = bias ? bias[col] : 0.0f;
#pragma unroll
            for (int r = 0; r < 4; ++r) {
                long long row = rowBase + waveM + mi * 16 + quad * 4 + r;
                float f = acc[mi][ni][r] + bv;
                long long off = row * ldc + col;
                if (SPLITOUT) {
                    u16 h = f2bf(f);
                    ((u16*)C)[off] = h;
                    Cl[off] = f2bf(f - bf2f(h));
                } else {
                    ((float*)C)[off] = f;
                }
            }
        }
    }
}

// ---------- single-precision bf16 GEMM, BK=64 (R11) ----------
template<bool OUTF32>
__global__ void gemm_bf(const u16* __restrict__ A, const u16* __restrict__ B,
                        const float* __restrict__ bias, void* __restrict__ C,
                        int K, long long lda, long long ldb, long long ldc,
                        int xcx)
{
    __shared__ u16 sm[2][2][TILE2];   // 64KB
    const int t = threadIdx.x;
    const int wave = t >> 6, lane = t & 63, quad = lane >> 4, l16 = lane & 15;
    const int waveM = (wave & 1) * 64, waveN = (wave >> 1) * 64;
    int bx, by;
    remap_xy(xcx, bx, by);
    const long long rowBase = (long long)by * BM;
    const long long colBase = (long long)bx * BN;
    A += rowBase * lda;
    B += colBase * ldb;

    f32x4 acc[4][4];
#pragma unroll
    for (int i = 0; i < 4; ++i)
#pragma unroll
        for (int j = 0; j < 4; ++j) acc[i][j] = (f32x4){0.f, 0.f, 0.f, 0.f};

    auto stage2 = [&](int buf, int k0) {   // 8 gload16 per thread
        stage_tile64(sm[buf][0], A, lda, k0, wave, lane);
        stage_tile64(sm[buf][1], B, ldb, k0, wave, lane);
    };

    stage2(0, 0);
    int cur = 0;
    for (int k0 = 0; k0 < K; k0 += BK2) {
        if (k0 + BK2 < K) {
            stage2(cur ^ 1, k0 + BK2);
            WAIT8_BARRIER();
        } else {
            WAIT0_BARRIER();
        }

#pragma unroll
        for (int kw = 0; kw < 2; ++kw) {
            bf16x8 af[4], bfr[4];
#pragma unroll
            for (int mi = 0; mi < 4; ++mi) af[mi]  = frag64(sm[cur][0], waveM + mi * 16 + l16, quad, kw);
#pragma unroll
            for (int ni = 0; ni < 4; ++ni) bfr[ni] = frag64(sm[cur][1], waveN + ni * 16 + l16, quad, kw);
#pragma unroll
            for (int mi = 0; mi < 4; ++mi)
#pragma unroll
                for (int ni = 0; ni < 4; ++ni)
                    acc[mi][ni] = __builtin_amdgcn_mfma_f32_16x16x32_bf16(af[mi], bfr[ni], acc[mi][ni], 0, 0, 0);
        }

        BARRIER();
        cur ^= 1;
    }

#pragma unroll
    for (int mi = 0; mi < 4; ++mi) {
#pragma unroll
        for (int ni = 0; ni < 4; ++ni) {
            long long col = colBase + waveN + ni * 16 + l16;
            float bv = bias ? bias[col] : 0.0f;
#pragma unroll
            for (int r = 0; r < 4; ++r) {
                long long row = rowBase + waveM + mi * 16 + quad * 4 + r;
                float f = acc[mi][ni][r] + bv;
                long long off = row * ldc + col;
                if (OUTF32) ((float*)C)[off] = f;
                else        ((u16*)C)[off] = f2bf(f);
            }
        }
    }
}

// ---------- PV GEMM, split-K z=4, no atomics, BK=64, XCD-aligned ----------
// (bx,by,bz) derived so the block reading weight rows [256*xcd,+256) runs on
// XCD xcd — matching softmax's row->XCD home (weights L2-hit).
__global__ void gemm_pv(const u16* __restrict__ A, const u16* __restrict__ B,
                        float* __restrict__ part, int KSEG,
                        long long lda, long long ldb)
{
    __shared__ u16 sm[2][2][TILE2];   // 64KB
    const int t = threadIdx.x;
    const int wave = t >> 6, lane = t & 63, quad = lane >> 4, l16 = lane & 15;
    const int waveM = (wave & 1) * 64, waveN = (wave >> 1) * 64;
    // bijective flat remap: 8 xcd x {2 by, 4 bx, 4 bz} = 256 blocks
    const int flat = (blockIdx.z * gridDim.y + blockIdx.y) * gridDim.x + blockIdx.x;
    const int xcd = flat & 7, i = flat >> 3;
    const int by = 2 * xcd + (i & 1);
    const int bx = (i >> 1) & 3;
    const int bz = i >> 3;
    const long long rowBase = (long long)by * BM;
    const long long colBase = (long long)bx * BN;
    const int kbase = bz * KSEG;
    A += rowBase * lda;
    B += colBase * ldb;

    f32x4 acc[4][4];
#pragma unroll
    for (int i2 = 0; i2 < 4; ++i2)
#pragma unroll
        for (int j = 0; j < 4; ++j) acc[i2][j] = (f32x4){0.f, 0.f, 0.f, 0.f};

    auto stage2 = [&](int buf, int k0) {
        stage_tile64(sm[buf][0], A, lda, k0, wave, lane);
        stage_tile64(sm[buf][1], B, ldb, k0, wave, lane);
    };

    stage2(0, kbase);
    int cur = 0;
    for (int k0 = kbase; k0 < kbase + KSEG; k0 += BK2) {
        if (k0 + BK2 < kbase + KSEG) {
            stage2(cur ^ 1, k0 + BK2);
            WAIT8_BARRIER();
        } else {
            WAIT0_BARRIER();
        }

#pragma unroll
        for (int kw = 0; kw < 2; ++kw) {
            bf16x8 af[4], bfr[4];
#pragma unroll
            for (int mi = 0; mi < 4; ++mi) af[mi]  = frag64(sm[cur][0], waveM + mi * 16 + l16, quad, kw);
#pragma unroll
            for (int ni = 0; ni < 4; ++ni) bfr[ni] = frag64(sm[cur][1], waveN + ni * 16 + l16, quad, kw);
#pragma unroll
            for (int mi = 0; mi < 4; ++mi)
#pragma unroll
                for (int ni = 0; ni < 4; ++ni)
                    acc[mi][ni] = __builtin_amdgcn_mfma_f32_16x16x32_bf16(af[mi], bfr[ni], acc[mi][ni], 0, 0, 0);
        }

        BARRIER();
        cur ^= 1;
    }

#pragma unroll
    for (int mi = 0; mi < 4; ++mi) {
#pragma unroll
        for (int ni = 0; ni < 4; ++ni) {
            long long col = colBase + waveN + ni * 16 + l16;
#pragma unroll
            for (int r = 0; r < 4; ++r) {
                long long row = rowBase + waveM + mi * 16 + quad * 4 + r;
                part[row * 4096 + 2048 + bz * 512 + col] = acc[mi][ni][r];
            }
        }
    }
}

// Sum 4 z-partials per element, write bf16 Att. Grid 2048 x 128 threads.
__global__ void cvt_att(const float* __restrict__ Sc, u16* __restrict__ dst)
{
    const int row = blockIdx.x, t = threadIdx.x;
    const float* p = Sc + (long long)row * 4096 + 2048 + t * 4;
    float4 s0 = *(const float4*)(p);
    float4 s1 = *(const float4*)(p + 512);
    float4 s2 = *(const float4*)(p + 1024);
    float4 s3 = *(const float4*)(p + 1536);
    u16x4 v;
    v[0] = f2bf(s0.x + s1.x + s2.x + s3.x);
    v[1] = f2bf(s0.y + s1.y + s2.y + s3.y);
    v[2] = f2bf(s0.z + s1.z + s2.z + s3.z);
    v[3] = f2bf(s0.w + s1.w + s2.w + s3.w);
    *(u16x4*)(dst + (long long)row * 512 + t * 4) = v;
}

// ---------- fp32 -> bf16 hi/lo split, 8 elems/thread ----------
__global__ void split32(const float* __restrict__ src, u16* __restrict__ h,
                        u16* __restrict__ l, long long n)
{
    long long i = ((long long)blockIdx.x * blockDim.x + threadIdx.x) * 8;
    if (i >= n) return;
    float4 a = *(const float4*)(src + i);
    float4 b = *(const float4*)(src + i + 4);
    float v[8] = {a.x, a.y, a.z, a.w, b.x, b.y, b.z, b.w};
    u16x8 hv, lv;
#pragma unroll
    for (int j = 0; j < 8; ++j) {
        u16 hh = f2bf(v[j]);
        hv[j] = hh;
        lv[j] = f2bf(v[j] - bf2f(hh));
    }
    *(u16x8*)(h + i) = hv;
    *(u16x8*)(l + i) = lv;
}

// ---------- fp32 -> bf16 (hi only), 8 elems/thread ----------
__global__ void cvt32(const float* __restrict__ src, u16* __restrict__ dst, long long n)
{
    long long i = ((long long)blockIdx.x * blockDim.x + threadIdx.x) * 8;
    if (i >= n) return;
    float4 a = *(const float4*)(src + i);
    float4 b = *(const float4*)(src + i + 4);
    u16x8 v;
    v[0] = f2bf(a.x); v[1] = f2bf(a.y); v[2] = f2bf(a.z); v[3] = f2bf(a.w);
    v[4] = f2bf(b.x); v[5] = f2bf(b.y); v[6] = f2bf(b.z); v[7] = f2bf(b.w);
    *(u16x8*)(dst + i) = v;
}

// Fused per-batch memory prep: one pass over src [4096,512] fp32 ->
//   Mh/Ml [4096,512] bf16 hi/lo  +  MemT [512,4096] bf16 (transposed hi).
__global__ void prep_mem(const float* __restrict__ src, u16* __restrict__ h,
                         u16* __restrict__ l, u16* __restrict__ tdst)
{
    __shared__ u16 tile[64][72];
    const int dBase = blockIdx.x * 64, mBase = blockIdx.y * 64;
    const int t = threadIdx.x;
#pragma unroll
    for (int i = 0; i < 4; ++i) {
        int seg = t + i * 256;
        int r = seg >> 4;                 // m-local
        int c = (seg & 15) << 2;          // d-local
        long long off = (long long)(mBase + r) * 512 + dBase + c;
        float4 v = *(const float4*)(src + off);
        u16 h0 = f2bf(v.x), h1 = f2bf(v.y), h2 = f2bf(v.z), h3 = f2bf(v.w);
        tile[r][c] = h0; tile[r][c + 1] = h1; tile[r][c + 2] = h2; tile[r][c + 3] = h3;
        u16x4 hv; hv[0] = h0; hv[1] = h1; hv[2] = h2; hv[3] = h3;
        u16x4 lv;
        lv[0] = f2bf(v.x - bf2f(h0)); lv[1] = f2bf(v.y - bf2f(h1));
        lv[2] = f2bf(v.z - bf2f(h2)); lv[3] = f2bf(v.w - bf2f(h3));
        *(u16x4*)(h + off) = hv;
        *(u16x4*)(l + off) = lv;
    }
    __syncthreads();
#pragma unroll
    for (int i = 0; i < 2; ++i) {
        int seg = t + i * 256;
        int r = seg >> 3;          // d-local
        int c = (seg & 7) << 3;    // m-local
        u16x8 v;
#pragma unroll
        for (int j = 0; j < 8; ++j) v[j] = tile[c + j][r];
        *(u16x8*)(tdst + (long long)(dBase + r) * 4096 + mBase + c) = v;
    }
}

// One block per score row; writes normalized bf16 weights in place (first
// 8KB of the row's 16KB slot). R11: block d handles row (d&7)*256 + (d>>3)
// so rows [256k, 256k+256) are processed (written) on XCD k — aligned with
// gemm_pv's reader mapping.
__global__ void softmax_rows(float* __restrict__ S)
{
    const int d = blockIdx.x;
    const int rowIdx = (d & 7) * 256 + (d >> 3);
    float* p = S + (long long)rowIdx * 4096;
    const int t = threadIdx.x;

    float4 v[4];
#pragma unroll
    for (int i = 0; i < 4; ++i) v[i] = ((const float4*)p)[t + i * 256];

    float m = -1e30f;
#pragma unroll
    for (int i = 0; i < 4; ++i)
        m = fmaxf(m, fmaxf(fmaxf(v[i].x, v[i].y), fmaxf(v[i].z, v[i].w)));
#pragma unroll
    for (int off = 32; off; off >>= 1) m = fmaxf(m, __shfl_xor(m, off));
    __shared__ float redm[4];
    if ((t & 63) == 0) redm[t >> 6] = m;
    __syncthreads();
    m = fmaxf(fmaxf(redm[0], redm[1]), fmaxf(redm[2], redm[3]));

    float s = 0.f;
#pragma unroll
    for (int i = 0; i < 4; ++i) {
        v[i].x = __expf(v[i].x - m); v[i].y = __expf(v[i].y - m);
        v[i].z = __expf(v[i].z - m); v[i].w = __expf(v[i].w - m);
        s += v[i].x + v[i].y + v[i].z + v[i].w;
    }
#pragma unroll
    for (int off = 32; off; off >>= 1) s += __shfl_xor(s, off);
    __shared__ float reds[4];
    if ((t & 63) == 0) reds[t >> 6] = s;
    __syncthreads();
    s = reds[0] + reds[1] + reds[2] + reds[3];
    const float inv = 1.0f / s;

    u16* pw = (u16*)p;
#pragma unroll
    for (int i = 0; i < 4; ++i) {
        u16x4 w;
        w[0] = f2bf(v[i].x * inv); w[1] = f2bf(v[i].y * inv);
        w[2] = f2bf(v[i].z * inv); w[3] = f2bf(v[i].w * inv);
        *(u16x4*)(pw + 4 * (t + i * 256)) = w;
    }
}

extern "C" void kernel_launch(void* const* d_in, const int* in_sizes, int n_in,
                              void* d_out, int out_size, void* d_ws, size_t ws_size,
                              hipStream_t stream)
{
    const float* x   = (const float*)d_in[0];   // [4,2048,1024] fp32
    const float* mem = (const float*)d_in[1];   // [4,4096,512]  fp32
    const float* Wq  = (const float*)d_in[2];   // [512,1024]    fp32
    const float* bq  = (const float*)d_in[3];   // [512]         fp32
    const float* Wm  = (const float*)d_in[4];   // [1024,512]    fp32
    const float* bm  = (const float*)d_in[5];   // [1024]        fp32

    // d_out (64MB) scratch schedule — every region dead before its final producer:
    //  [ 0, 8)  Qh  bf16 [8192,512]  (cvt_att overwrites batch rows with bf16 Att)
    //  [ 8,16)  Ql  bf16 [8192,512]
    //  [16,24)  Mh/Ml bf16 [4096,512] each (per batch)
    //  [24,28)  MemT bf16 [512,4096]
    //  [28,29)  Wqh, [29,30) Wql, [30,31) Wmh
    //  [32,64)  Xh/Xl (pre-loop) -> Sc fp32 [2048,4096] (in-loop; each row slot:
    //           [0,8K) bf16 weights, [8K,16K) fp32 PV z-partials) -> out1 (final)
    char* base = (char*)d_out;
    u16*   Qh   = (u16*)base;
    u16*   Ql   = (u16*)(base + (8ll  << 20));
    u16*   Mh   = (u16*)(base + (16ll << 20));
    u16*   Ml   = (u16*)(base + (20ll << 20));
    u16*   MemT = (u16*)(base + (24ll << 20));
    u16*   Wqh  = (u16*)(base + (28ll << 20));
    u16*   Wql  = (u16*)(base + (29ll << 20));
    u16*   Wmh  = (u16*)(base + (30ll << 20));
    u16*   Xh   = (u16*)(base + (32ll << 20));
    u16*   Xl   = (u16*)(base + (48ll << 20));
    float* Sc   = (float*)(base + (32ll << 20));
    float* out1 = (float*)d_out + 8388608ll;

    // one-time hi/lo splits (identical rounding to the verified in-GEMM split)
    split32<<<4096, 256, 0, stream>>>(x,  Xh,  Xl,  8192ll * 1024);
    split32<<<256,  256, 0, stream>>>(Wq, Wqh, Wql, 512ll * 1024);
    cvt32<<<256,    256, 0, stream>>>(Wm, Wmh,      1024ll * 512);

    // Qh/Ql = split(x @ Wq^T + bq)   [8192,512], K=1024; grid (4,64)
    gemm_cat3<true><<<dim3(512 / BN, 8192 / BM), 256, 0, stream>>>(
        Xh, Xl, Wqh, Wql, bq, Qh, Ql, 1024, 1024, 1024, 512, 1);

    for (int b = 0; b < 4; ++b) {
        const float* Mb = mem + (long long)b * 4096 * 512;
        u16* Qhb = Qh + (long long)b * 2048 * 512;
        u16* Qlb = Ql + (long long)b * 2048 * 512;

        // fused split + transpose: one pass over Mb
        prep_mem<<<dim3(8, 64), 256, 0, stream>>>(Mb, Mh, Ml, MemT);

        // Sc = Qb @ Mb^T  [2048,4096], K=512; grid (32,16), xcx=4
        gemm_cat3<false><<<dim3(4096 / BN, 2048 / BM), 256, 0, stream>>>(
            Qhb, Qlb, Mh, Ml, nullptr, Sc, nullptr, 512, 512, 512, 4096, 4);

        // softmax rows -> bf16 weights in place (XCD-aligned row mapping)
        softmax_rows<<<dim3(2048), 256, 0, stream>>>(Sc);

        // PV partials (no atomics): grid (4,16,4), KSEG=1024, BK=64
        gemm_pv<<<dim3(512 / BN, 2048 / BM, 4), 256, 0, stream>>>(
            (const u16*)Sc, MemT, Sc, 1024, 8192, 4096);

        // sum z-partials -> bf16 Att into dead Q rows (ldc=512 contiguous)
        cvt_att<<<dim3(2048), 128, 0, stream>>>(Sc, Qhb);
    }

    // out1 = Att @ Wm^T + bm   [8192,1024], K=512; grid (8,64), BK=64
    gemm_bf<true><<<dim3(1024 / BN, 8192 / BM), 256, 0, stream>>>(
        Qh, Wmh, bm, out1, 512, 512, 512, 1024, 1);

    // out0 = x (exact fp32 copy; overwrites dead scratch in [0,32MB)). Must be last.
    hipMemcpyAsync(d_out, x, 8192ll * 1024 * 4, hipMemcpyDeviceToDevice, stream);
}

// Round 12
// 388.267 us; speedup vs baseline: 1.4266x; 1.1625x over previous
//
#include <hip/hip_runtime.h>

typedef unsigned short u16;
typedef __bf16 bf16x8 __attribute__((ext_vector_type(8)));
typedef float f32x4 __attribute__((ext_vector_type(4)));
typedef unsigned short u16x8 __attribute__((ext_vector_type(8)));
typedef unsigned short u16x4 __attribute__((ext_vector_type(4)));

__device__ __forceinline__ u16 f2bf(float f) {
    unsigned u = __builtin_bit_cast(unsigned, f);
    u += 0x7FFFu + ((u >> 16) & 1u);   // RNE
    return (u16)(u >> 16);
}
__device__ __forceinline__ float bf2f(u16 s) {
    return __builtin_bit_cast(float, ((unsigned)s) << 16);
}

// async 16B global->LDS. LDS dest = wave-uniform base + lane*16B (m97/m104).
__device__ __forceinline__ void gload16(u16* lds, const u16* g) {
    __builtin_amdgcn_global_load_lds(
        (__attribute__((address_space(1))) unsigned*)g,
        (__attribute__((address_space(3))) unsigned*)lds,
        16, 0, 0);
}

// XCD-chunked tile remap (T1): dispatch id d -> XCD d&7 (verified R7:
// FETCH 66->25MB). Uses x/y only; batched z-slices are ≡0 mod 8 blocks so
// per-slice XCD assignment is unchanged.
__device__ __forceinline__ void remap_xy(int xcx, int& bx, int& by) {
    const int nx = gridDim.x;
    const int d = blockIdx.y * nx + blockIdx.x;
    const int xcd = d & 7, i = d >> 3;
    const int xcy = 8 / xcx;
    const int cw = nx / xcx;
    const int ch = (int)gridDim.y / xcy;
    bx = (xcd % xcx) * cw + i % cw;
    by = (xcd / xcx) * ch + i / cw;
}

#define BM 128
#define BN 128
#define BK 32
#define TILE (BM * BK)    // 8KB tile for BK=32 path (cat3)
#define BK2 64
#define TILE2 (BM * BK2)  // 16KB tile for BK=64 path (bf/pv; verified R11)

// ---- BK=32 staging/frag (cat3; verified R7-R11: 0 bank conflicts) ----
__device__ __forceinline__ void stage_tile(u16* lds, const u16* src, long long ld,
                                           int k0, int wave, int lane)
{
#pragma unroll
    for (int i = 0; i < 2; ++i) {
        const int segb = wave * 64 + i * 256;   // wave-uniform
        const int seg  = segb + lane;
        const int r  = seg >> 2;
        const int qs = seg & 3;
        const int qg = qs ^ ((r >> 1) & 3);     // pre-swizzled global k-slot
        gload16(lds + segb * 8, src + (long long)r * ld + k0 + qg * 8);
    }
}
__device__ __forceinline__ bf16x8 frag(const u16* lds, int row, int quad) {
    const int slot = quad ^ ((row >> 1) & 3);
    return __builtin_bit_cast(bf16x8, *(const u16x8*)(lds + row * BK + slot * 8));
}

// ---- BK=64 staging/frag (bf/pv; verified R11) ----
__device__ __forceinline__ void stage_tile64(u16* lds, const u16* src, long long ld,
                                             int k0, int wave, int lane)
{
#pragma unroll
    for (int i = 0; i < 4; ++i) {
        const int segb = wave * 64 + i * 256;   // wave-uniform
        const int seg  = segb + lane;
        const int r  = seg >> 3;
        const int qs = seg & 7;
        const int qg = qs ^ (r & 7);            // pre-swizzled global k-slot
        gload16(lds + segb * 8, src + (long long)r * ld + k0 + qg * 8);
    }
}
__device__ __forceinline__ bf16x8 frag64(const u16* lds, int row, int quad, int kw) {
    const int slot = (kw * 4 + quad) ^ (row & 7);
    return __builtin_bit_cast(bf16x8, *(const u16x8*)(lds + row * BK2 + slot * 8));
}

// Counted-vmcnt barrier pair (T4, verified R10).
#define WAIT8_BARRIER()  asm volatile("s_waitcnt vmcnt(8)\n\ts_barrier" ::: "memory")
#define WAIT0_BARRIER()  asm volatile("s_waitcnt vmcnt(0)\n\ts_barrier" ::: "memory")
#define BARRIER()        asm volatile("s_barrier" ::: "memory")

// ---------- emulated-fp32 GEMM, 3 terms interleaved per K-tile ----------
// Internals IDENTICAL to R11 (635 TF = 2-phase ceiling; 8-phase port is the
// next structural step). R12 adds only batch strides (blockIdx.z).
template<bool SPLITOUT>
__global__ void gemm_cat3(const u16* __restrict__ Ah, const u16* __restrict__ Al,
                          const u16* __restrict__ Bh, const u16* __restrict__ Bl,
                          const float* __restrict__ bias,
                          void* __restrict__ C, u16* __restrict__ Cl,
                          int K, long long lda, long long ldb, long long ldc,
                          int xcx, long long abstride, long long bbstride,
                          long long cbstride)
{
    __shared__ u16 sm[2][4][TILE];   // 64KB
    const int t = threadIdx.x;
    const int wave = t >> 6, lane = t & 63, quad = lane >> 4, l16 = lane & 15;
    const int waveM = (wave & 1) * 64, waveN = (wave >> 1) * 64;
    const int batch = blockIdx.z;
    Ah += batch * abstride; Al += batch * abstride;
    Bh += batch * bbstride; Bl += batch * bbstride;
    void* Cb = SPLITOUT ? C : (void*)((float*)C + (long long)batch * cbstride);
    int bx, by;
    remap_xy(xcx, bx, by);
    const long long rowBase = (long long)by * BM;
    const long long colBase = (long long)bx * BN;
    Ah += rowBase * lda; Al += rowBase * lda;
    Bh += colBase * ldb; Bl += colBase * ldb;

    f32x4 acc[4][4];
#pragma unroll
    for (int i = 0; i < 4; ++i)
#pragma unroll
        for (int j = 0; j < 4; ++j) acc[i][j] = (f32x4){0.f, 0.f, 0.f, 0.f};

    auto stage4 = [&](int buf, int k0) {   // 8 gload16 per thread
        stage_tile(sm[buf][0], Ah, lda, k0, wave, lane);
        stage_tile(sm[buf][1], Al, lda, k0, wave, lane);
        stage_tile(sm[buf][2], Bh, ldb, k0, wave, lane);
        stage_tile(sm[buf][3], Bl, ldb, k0, wave, lane);
    };

    stage4(0, 0);
    int cur = 0;
    for (int k0 = 0; k0 < K; k0 += BK) {
        if (k0 + BK < K) {
            stage4(cur ^ 1, k0 + BK);
            WAIT8_BARRIER();
        } else {
            WAIT0_BARRIER();
        }

        bf16x8 ah[4], al[4], bh[4], bl[4];
#pragma unroll
        for (int mi = 0; mi < 4; ++mi) {
            int row = waveM + mi * 16 + l16;
            ah[mi] = frag(sm[cur][0], row, quad);
            al[mi] = frag(sm[cur][1], row, quad);
        }
#pragma unroll
        for (int ni = 0; ni < 4; ++ni) {
            int row = waveN + ni * 16 + l16;
            bh[ni] = frag(sm[cur][2], row, quad);
            bl[ni] = frag(sm[cur][3], row, quad);
        }
#pragma unroll
        for (int mi = 0; mi < 4; ++mi)
#pragma unroll
            for (int ni = 0; ni < 4; ++ni) {
                acc[mi][ni] = __builtin_amdgcn_mfma_f32_16x16x32_bf16(al[mi], bh[ni], acc[mi][ni], 0, 0, 0);
                acc[mi][ni] = __builtin_amdgcn_mfma_f32_16x16x32_bf16(ah[mi], bl[ni], acc[mi][ni], 0, 0, 0);
                acc[mi][ni] = __builtin_amdgcn_mfma_f32_16x16x32_bf16(ah[mi], bh[ni], acc[mi][ni], 0, 0, 0);
            }

        BARRIER();
        cur ^= 1;
    }

#pragma unroll
    for (int mi = 0; mi < 4; ++mi) {
#pragma unroll
        for (int ni = 0; ni < 4; ++ni) {
            long long col = colBase + waveN + ni * 16 + l16;
            float bv = bias ? bias[col] : 0.0f;
#pragma unroll
            for (int r = 0; r < 4; ++r) {
                long long row = rowBase + waveM + mi * 16 + quad * 4 + r;
                float f = acc[mi][ni][r] + bv;
                long long off = row * ldc + col;
                if (SPLITOUT) {
                    u16 h = f2bf(f);
                    ((u16*)Cb)[off] = h;
                    Cl[off] = f2bf(f - bf2f(h));
                } else {
                    ((float*)Cb)[off] = f;
                }
            }
        }
    }
}

// ---------- single-precision bf16 GEMM, BK=64 (verified R11) ----------
template<bool OUTF32>
__global__ void gemm_bf(const u16* __restrict__ A, const u16* __restrict__ B,
                        const float* __restrict__ bias, void* __restrict__ C,
                        int K, long long lda, long long ldb, long long ldc,
                        int xcx)
{
    __shared__ u16 sm[2][2][TILE2];   // 64KB
    const int t = threadIdx.x;
    const int wave = t >> 6, lane = t & 63, quad = lane >> 4, l16 = lane & 15;
    const int waveM = (wave & 1) * 64, waveN = (wave >> 1) * 64;
    int bx, by;
    remap_xy(xcx, bx, by);
    const long long rowBase = (long long)by * BM;
    const long long colBase = (long long)bx * BN;
    A += rowBase * lda;
    B += colBase * ldb;

    f32x4 acc[4][4];
#pragma unroll
    for (int i = 0; i < 4; ++i)
#pragma unroll
        for (int j = 0; j < 4; ++j) acc[i][j] = (f32x4){0.f, 0.f, 0.f, 0.f};

    auto stage2 = [&](int buf, int k0) {   // 8 gload16 per thread
        stage_tile64(sm[buf][0], A, lda, k0, wave, lane);
        stage_tile64(sm[buf][1], B, ldb, k0, wave, lane);
    };

    stage2(0, 0);
    int cur = 0;
    for (int k0 = 0; k0 < K; k0 += BK2) {
        if (k0 + BK2 < K) {
            stage2(cur ^ 1, k0 + BK2);
            WAIT8_BARRIER();
        } else {
            WAIT0_BARRIER();
        }

#pragma unroll
        for (int kw = 0; kw < 2; ++kw) {
            bf16x8 af[4], bfr[4];
#pragma unroll
            for (int mi = 0; mi < 4; ++mi) af[mi]  = frag64(sm[cur][0], waveM + mi * 16 + l16, quad, kw);
#pragma unroll
            for (int ni = 0; ni < 4; ++ni) bfr[ni] = frag64(sm[cur][1], waveN + ni * 16 + l16, quad, kw);
#pragma unroll
            for (int mi = 0; mi < 4; ++mi)
#pragma unroll
                for (int ni = 0; ni < 4; ++ni)
                    acc[mi][ni] = __builtin_amdgcn_mfma_f32_16x16x32_bf16(af[mi], bfr[ni], acc[mi][ni], 0, 0, 0);
        }

        BARRIER();
        cur ^= 1;
    }

#pragma unroll
    for (int mi = 0; mi < 4; ++mi) {
#pragma unroll
        for (int ni = 0; ni < 4; ++ni) {
            long long col = colBase + waveN + ni * 16 + l16;
            float bv = bias ? bias[col] : 0.0f;
#pragma unroll
            for (int r = 0; r < 4; ++r) {
                long long row = rowBase + waveM + mi * 16 + quad * 4 + r;
                float f = acc[mi][ni][r] + bv;
                long long off = row * ldc + col;
                if (OUTF32) ((float*)C)[off] = f;
                else        ((u16*)C)[off] = f2bf(f);
            }
        }
    }
}

// ---------- PV GEMM, split-K z=4, no atomics, BK=64, XCD-aligned ----------
// flat id decomposition: xcd = flat&7; i = flat>>3; j = i&31 gives
// {by,bx,bz} as in R11; batch = i>>5 (0 in fallback). Block reading weight
// rows [256*xcd,+256) runs on XCD xcd (matches softmax's writer mapping).
__global__ void gemm_pv(const u16* __restrict__ A, const u16* __restrict__ B,
                        float* __restrict__ part, int KSEG,
                        long long lda, long long ldb,
                        long long abstride, long long bbstride, long long pbstride)
{
    __shared__ u16 sm[2][2][TILE2];   // 64KB
    const int t = threadIdx.x;
    const int wave = t >> 6, lane = t & 63, quad = lane >> 4, l16 = lane & 15;
    const int waveM = (wave & 1) * 64, waveN = (wave >> 1) * 64;
    const int flat = (blockIdx.z * gridDim.y + blockIdx.y) * gridDim.x + blockIdx.x;
    const int xcd = flat & 7, i = flat >> 3;
    const int batch = i >> 5;
    const int j = i & 31;
    const int by = 2 * xcd + (j & 1);
    const int bx = (j >> 1) & 3;
    const int bz = j >> 3;
    A += batch * abstride; B += batch * bbstride; part += batch * pbstride;
    const long long rowBase = (long long)by * BM;
    const long long colBase = (long long)bx * BN;
    const int kbase = bz * KSEG;
    A += rowBase * lda;
    B += colBase * ldb;

    f32x4 acc[4][4];
#pragma unroll
    for (int i2 = 0; i2 < 4; ++i2)
#pragma unroll
        for (int j2 = 0; j2 < 4; ++j2) acc[i2][j2] = (f32x4){0.f, 0.f, 0.f, 0.f};

    auto stage2 = [&](int buf, int k0) {
        stage_tile64(sm[buf][0], A, lda, k0, wave, lane);
        stage_tile64(sm[buf][1], B, ldb, k0, wave, lane);
    };

    stage2(0, kbase);
    int cur = 0;
    for (int k0 = kbase; k0 < kbase + KSEG; k0 += BK2) {
        if (k0 + BK2 < kbase + KSEG) {
            stage2(cur ^ 1, k0 + BK2);
            WAIT8_BARRIER();
        } else {
            WAIT0_BARRIER();
        }

#pragma unroll
        for (int kw = 0; kw < 2; ++kw) {
            bf16x8 af[4], bfr[4];
#pragma unroll
            for (int mi = 0; mi < 4; ++mi) af[mi]  = frag64(sm[cur][0], waveM + mi * 16 + l16, quad, kw);
#pragma unroll
            for (int ni = 0; ni < 4; ++ni) bfr[ni] = frag64(sm[cur][1], waveN + ni * 16 + l16, quad, kw);
#pragma unroll
            for (int mi = 0; mi < 4; ++mi)
#pragma unroll
                for (int ni = 0; ni < 4; ++ni)
                    acc[mi][ni] = __builtin_amdgcn_mfma_f32_16x16x32_bf16(af[mi], bfr[ni], acc[mi][ni], 0, 0, 0);
        }

        BARRIER();
        cur ^= 1;
    }

#pragma unroll
    for (int mi = 0; mi < 4; ++mi) {
#pragma unroll
        for (int ni = 0; ni < 4; ++ni) {
            long long col = colBase + waveN + ni * 16 + l16;
#pragma unroll
            for (int r = 0; r < 4; ++r) {
                long long row = rowBase + waveM + mi * 16 + quad * 4 + r;
                part[row * 4096 + 2048 + bz * 512 + col] = acc[mi][ni][r];
            }
        }
    }
}

// Sum 4 z-partials per element, write bf16 Att. batch = blockIdx.x>>11.
__global__ void cvt_att(const float* __restrict__ Sc, u16* __restrict__ dst,
                        long long sbstride, long long dbstride)
{
    const int d = blockIdx.x, t = threadIdx.x;
    const int batch = d >> 11, row = d & 2047;
    const float* p = Sc + (long long)batch * sbstride + (long long)row * 4096 + 2048 + t * 4;
    float4 s0 = *(const float4*)(p);
    float4 s1 = *(const float4*)(p + 512);
    float4 s2 = *(const float4*)(p + 1024);
    float4 s3 = *(const float4*)(p + 1536);
    u16x4 v;
    v[0] = f2bf(s0.x + s1.x + s2.x + s3.x);
    v[1] = f2bf(s0.y + s1.y + s2.y + s3.y);
    v[2] = f2bf(s0.z + s1.z + s2.z + s3.z);
    v[3] = f2bf(s0.w + s1.w + s2.w + s3.w);
    *(u16x4*)(dst + (long long)batch * dbstride + (long long)row * 512 + t * 4) = v;
}

// ---------- fp32 -> bf16 hi/lo split, 8 elems/thread ----------
__global__ void split32(const float* __restrict__ src, u16* __restrict__ h,
                        u16* __restrict__ l, long long n)
{
    long long i = ((long long)blockIdx.x * blockDim.x + threadIdx.x) * 8;
    if (i >= n) return;
    float4 a = *(const float4*)(src + i);
    float4 b = *(const float4*)(src + i + 4);
    float v[8] = {a.x, a.y, a.z, a.w, b.x, b.y, b.z, b.w};
    u16x8 hv, lv;
#pragma unroll
    for (int j = 0; j < 8; ++j) {
        u16 hh = f2bf(v[j]);
        hv[j] = hh;
        lv[j] = f2bf(v[j] - bf2f(hh));
    }
    *(u16x8*)(h + i) = hv;
    *(u16x8*)(l + i) = lv;
}

// ---------- fp32 -> bf16 (hi only), 8 elems/thread ----------
__global__ void cvt32(const float* __restrict__ src, u16* __restrict__ dst, long long n)
{
    long long i = ((long long)blockIdx.x * blockDim.x + threadIdx.x) * 8;
    if (i >= n) return;
    float4 a = *(const float4*)(src + i);
    float4 b = *(const float4*)(src + i + 4);
    u16x8 v;
    v[0] = f2bf(a.x); v[1] = f2bf(a.y); v[2] = f2bf(a.z); v[3] = f2bf(a.w);
    v[4] = f2bf(b.x); v[5] = f2bf(b.y); v[6] = f2bf(b.z); v[7] = f2bf(b.w);
    *(u16x8*)(dst + i) = v;
}

// Fused per-batch memory prep (batch = blockIdx.z): one pass over src
// [4096,512] fp32 -> Mh/Ml bf16 hi/lo + MemT [512,4096] bf16 (transposed hi).
__global__ void prep_mem(const float* __restrict__ src, u16* __restrict__ h,
                         u16* __restrict__ l, u16* __restrict__ tdst,
                         long long sstride, long long mstride, long long tstride)
{
    __shared__ u16 tile[64][72];
    const int batch = blockIdx.z;
    src += batch * sstride; h += batch * mstride; l += batch * mstride;
    tdst += batch * tstride;
    const int dBase = blockIdx.x * 64, mBase = blockIdx.y * 64;
    const int t = threadIdx.x;
#pragma unroll
    for (int i = 0; i < 4; ++i) {
        int seg = t + i * 256;
        int r = seg >> 4;                 // m-local
        int c = (seg & 15) << 2;          // d-local
        long long off = (long long)(mBase + r) * 512 + dBase + c;
        float4 v = *(const float4*)(src + off);
        u16 h0 = f2bf(v.x), h1 = f2bf(v.y), h2 = f2bf(v.z), h3 = f2bf(v.w);
        tile[r][c] = h0; tile[r][c + 1] = h1; tile[r][c + 2] = h2; tile[r][c + 3] = h3;
        u16x4 hv; hv[0] = h0; hv[1] = h1; hv[2] = h2; hv[3] = h3;
        u16x4 lv;
        lv[0] = f2bf(v.x - bf2f(h0)); lv[1] = f2bf(v.y - bf2f(h1));
        lv[2] = f2bf(v.z - bf2f(h2)); lv[3] = f2bf(v.w - bf2f(h3));
        *(u16x4*)(h + off) = hv;
        *(u16x4*)(l + off) = lv;
    }
    __syncthreads();
#pragma unroll
    for (int i = 0; i < 2; ++i) {
        int seg = t + i * 256;
        int r = seg >> 3;          // d-local
        int c = (seg & 7) << 3;    // m-local
        u16x8 v;
#pragma unroll
        for (int j = 0; j < 8; ++j) v[j] = tile[c + j][r];
        *(u16x8*)(tdst + (long long)(dBase + r) * 4096 + mBase + c) = v;
    }
}

// One block per score row. batch = blockIdx.x>>11; within-batch block d
// handles row (d&7)*256 + (d>>3) (XCD-aligned with gemm_pv's reader).
__global__ void softmax_rows(float* __restrict__ S, long long bstride)
{
    const int d = blockIdx.x;
    const int local = d & 2047, batch = d >> 11;
    const int rowIdx = (local & 7) * 256 + (local >> 3);
    float* p = S + (long long)batch * bstride + (long long)rowIdx * 4096;
    const int t = threadIdx.x;

    float4 v[4];
#pragma unroll
    for (int i = 0; i < 4; ++i) v[i] = ((const float4*)p)[t + i * 256];

    float m = -1e30f;
#pragma unroll
    for (int i = 0; i < 4; ++i)
        m = fmaxf(m, fmaxf(fmaxf(v[i].x, v[i].y), fmaxf(v[i].z, v[i].w)));
#pragma unroll
    for (int off = 32; off; off >>= 1) m = fmaxf(m, __shfl_xor(m, off));
    __shared__ float redm[4];
    if ((t & 63) == 0) redm[t >> 6] = m;
    __syncthreads();
    m = fmaxf(fmaxf(redm[0], redm[1]), fmaxf(redm[2], redm[3]));

    float s = 0.f;
#pragma unroll
    for (int i = 0; i < 4; ++i) {
        v[i].x = __expf(v[i].x - m); v[i].y = __expf(v[i].y - m);
        v[i].z = __expf(v[i].z - m); v[i].w = __expf(v[i].w - m);
        s += v[i].x + v[i].y + v[i].z + v[i].w;
    }
#pragma unroll
    for (int off = 32; off; off >>= 1) s += __shfl_xor(s, off);
    __shared__ float reds[4];
    if ((t & 63) == 0) reds[t >> 6] = s;
    __syncthreads();
    s = reds[0] + reds[1] + reds[2] + reds[3];
    const float inv = 1.0f / s;

    u16* pw = (u16*)p;
#pragma unroll
    for (int i = 0; i < 4; ++i) {
        u16x4 w;
        w[0] = f2bf(v[i].x * inv); w[1] = f2bf(v[i].y * inv);
        w[2] = f2bf(v[i].z * inv); w[3] = f2bf(v[i].w * inv);
        *(u16x4*)(pw + 4 * (t + i * 256)) = w;
    }
}

extern "C" void kernel_launch(void* const* d_in, const int* in_sizes, int n_in,
                              void* d_out, int out_size, void* d_ws, size_t ws_size,
                              hipStream_t stream)
{
    const float* x   = (const float*)d_in[0];   // [4,2048,1024] fp32
    const float* mem = (const float*)d_in[1];   // [4,4096,512]  fp32
    const float* Wq  = (const float*)d_in[2];   // [512,1024]    fp32
    const float* bq  = (const float*)d_in[3];   // [512]         fp32
    const float* Wm  = (const float*)d_in[4];   // [1024,512]    fp32
    const float* bm  = (const float*)d_in[5];   // [1024]        fp32

    // d_out (64MB):
    //  [ 0, 8) Qh, [ 8,16) Ql, [16,24) Mh/Ml (fallback only),
    //  [24,28) MemT (fallback), [28,29) Wqh, [29,30) Wql, [30,31) Wmh,
    //  [32,64) Xh/Xl (pre-Q-GEMM) -> Sc (fallback, in-loop) -> out1 (final)
    char* base = (char*)d_out;
    u16*   Qh   = (u16*)base;
    u16*   Ql   = (u16*)(base + (8ll  << 20));
    u16*   Mh   = (u16*)(base + (16ll << 20));
    u16*   Ml   = (u16*)(base + (20ll << 20));
    u16*   MemT = (u16*)(base + (24ll << 20));
    u16*   Wqh  = (u16*)(base + (28ll << 20));
    u16*   Wql  = (u16*)(base + (29ll << 20));
    u16*   Wmh  = (u16*)(base + (30ll << 20));
    u16*   Xh   = (u16*)(base + (32ll << 20));
    u16*   Xl   = (u16*)(base + (48ll << 20));
    float* Sc   = (float*)(base + (32ll << 20));
    float* out1 = (float*)d_out + 8388608ll;

    // one-time hi/lo splits
    split32<<<4096, 256, 0, stream>>>(x,  Xh,  Xl,  8192ll * 1024);
    split32<<<256,  256, 0, stream>>>(Wq, Wqh, Wql, 512ll * 1024);
    cvt32<<<256,    256, 0, stream>>>(Wm, Wmh,      1024ll * 512);

    // Qh/Ql = split(x @ Wq^T + bq)   [8192,512], K=1024; grid (4,64)
    gemm_cat3<true><<<dim3(512 / BN, 8192 / BM, 1), 256, 0, stream>>>(
        Xh, Xl, Wqh, Wql, bq, Qh, Ql, 1024, 1024, 1024, 512, 1, 0, 0, 0);

    // R12: batch all 4 attention batches into single dispatches using d_ws
    // (4x Mh/Ml/MemT = 48MB + 4x Sc = 128MB -> 176MB). Launches 22 -> 11.
    const bool big_ws = (d_ws != nullptr) && (ws_size >= (176ull << 20));
    if (big_ws) {
        char* wsb = (char*)d_ws;
        u16*   Mh4 = (u16*)wsb;                    // [4][4096,512]
        u16*   Ml4 = (u16*)(wsb + (16ll << 20));   // [4][4096,512]
        u16*   MT4 = (u16*)(wsb + (32ll << 20));   // [4][512,4096]
        float* Sc4 = (float*)(wsb + (48ll << 20)); // [4][2048,4096]

        prep_mem<<<dim3(8, 64, 4), 256, 0, stream>>>(
            mem, Mh4, Ml4, MT4, 4096ll * 512, 4096ll * 512, 512ll * 4096);

        gemm_cat3<false><<<dim3(4096 / BN, 2048 / BM, 4), 256, 0, stream>>>(
            Qh, Ql, Mh4, Ml4, nullptr, Sc4, nullptr, 512, 512, 512, 4096, 4,
            2048ll * 512, 4096ll * 512, 2048ll * 4096);

        softmax_rows<<<dim3(8192), 256, 0, stream>>>(Sc4, 2048ll * 4096);

        gemm_pv<<<dim3(4, 16, 16), 256, 0, stream>>>(
            (const u16*)Sc4, MT4, Sc4, 1024, 8192, 4096,
            2048ll * 8192, 512ll * 4096, 2048ll * 4096);

        cvt_att<<<dim3(8192), 128, 0, stream>>>(
            Sc4, Qh, 2048ll * 4096, 2048ll * 512);
    } else {
        for (int b = 0; b < 4; ++b) {
            const float* Mb = mem + (long long)b * 4096 * 512;
            u16* Qhb = Qh + (long long)b * 2048 * 512;
            u16* Qlb = Ql + (long long)b * 2048 * 512;

            prep_mem<<<dim3(8, 64, 1), 256, 0, stream>>>(
                Mb, Mh, Ml, MemT, 0, 0, 0);

            gemm_cat3<false><<<dim3(4096 / BN, 2048 / BM, 1), 256, 0, stream>>>(
                Qhb, Qlb, Mh, Ml, nullptr, Sc, nullptr, 512, 512, 512, 4096, 4,
                0, 0, 0);

            softmax_rows<<<dim3(2048), 256, 0, stream>>>(Sc, 0);

            gemm_pv<<<dim3(4, 16, 4), 256, 0, stream>>>(
                (const u16*)Sc, MemT, Sc, 1024, 8192, 4096, 0, 0, 0);

            cvt_att<<<dim3(2048), 128, 0, stream>>>(Sc, Qhb, 0, 0);
        }
    }

    // out1 = Att @ Wm^T + bm   [8192,1024], K=512; grid (8,64), BK=64
    gemm_bf<true><<<dim3(1024 / BN, 8192 / BM, 1), 256, 0, stream>>>(
        Qh, Wmh, bm, out1, 512, 512, 512, 1024, 1);

    // out0 = x (exact fp32 copy; overwrites dead scratch in [0,32MB)). Must be last.
    hipMemcpyAsync(d_out, x, 8192ll * 1024 * 4, hipMemcpyDeviceToDevice, stream);
}

// Round 13
// 379.520 us; speedup vs baseline: 1.4595x; 1.0230x over previous
//
#include <hip/hip_runtime.h>

typedef unsigned short u16;
typedef __bf16 bf16x8 __attribute__((ext_vector_type(8)));
typedef float f32x4 __attribute__((ext_vector_type(4)));
typedef unsigned short u16x8 __attribute__((ext_vector_type(8)));
typedef unsigned short u16x4 __attribute__((ext_vector_type(4)));

__device__ __forceinline__ u16 f2bf(float f) {
    unsigned u = __builtin_bit_cast(unsigned, f);
    u += 0x7FFFu + ((u >> 16) & 1u);   // RNE
    return (u16)(u >> 16);
}
__device__ __forceinline__ float bf2f(u16 s) {
    return __builtin_bit_cast(float, ((unsigned)s) << 16);
}

// async 16B global->LDS. LDS dest = wave-uniform base + lane*16B (m97/m104).
__device__ __forceinline__ void gload16(u16* lds, const u16* g) {
    __builtin_amdgcn_global_load_lds(
        (__attribute__((address_space(1))) unsigned*)g,
        (__attribute__((address_space(3))) unsigned*)lds,
        16, 0, 0);
}

// XCD-chunked tile remap (T1, verified R7: FETCH 66->25MB).
__device__ __forceinline__ void remap_xy(int xcx, int& bx, int& by) {
    const int nx = gridDim.x;
    const int d = blockIdx.y * nx + blockIdx.x;
    const int xcd = d & 7, i = d >> 3;
    const int xcy = 8 / xcx;
    const int cw = nx / xcx;
    const int ch = (int)gridDim.y / xcy;
    bx = (xcd % xcx) * cw + i % cw;
    by = (xcd / xcx) * ch + i / cw;
}

#define BM 128
#define BN 128
#define BK 32
#define TILE (BM * BK)    // 8KB tile, 512 x 16B segments
#define BK2 64
#define TILE2 (BM * BK2)  // 16KB tile, 1024 x 16B segments
// R13: GEMM blocks go 256 -> 512 threads (4 -> 8 waves). With counted-vmcnt
// (R10) the residual stall is per-wave load latency; doubling waves/CU
// (16 at same LDS) doubles latency-hiding agents. Wave tile 64x64 -> 64x32.

// ---- BK=32 staging/frag (verified R7-R12: 0 bank conflicts) ----
// 512 threads: one 16B segment per thread.
__device__ __forceinline__ void stage_tile(u16* lds, const u16* src, long long ld,
                                           int k0, int wave, int lane)
{
    const int segb = wave * 64;            // wave-uniform
    const int seg  = segb + lane;
    const int r  = seg >> 2;
    const int qs = seg & 3;
    const int qg = qs ^ ((r >> 1) & 3);    // pre-swizzled global k-slot
    gload16(lds + segb * 8, src + (long long)r * ld + k0 + qg * 8);
}
__device__ __forceinline__ bf16x8 frag(const u16* lds, int row, int quad) {
    const int slot = quad ^ ((row >> 1) & 3);
    return __builtin_bit_cast(bf16x8, *(const u16x8*)(lds + row * BK + slot * 8));
}

// ---- BK=64 staging/frag (verified R11) ---- 512 threads: two segs/thread.
__device__ __forceinline__ void stage_tile64(u16* lds, const u16* src, long long ld,
                                             int k0, int wave, int lane)
{
#pragma unroll
    for (int i = 0; i < 2; ++i) {
        const int segb = wave * 64 + i * 512;   // wave-uniform
        const int seg  = segb + lane;
        const int r  = seg >> 3;
        const int qs = seg & 7;
        const int qg = qs ^ (r & 7);            // pre-swizzled global k-slot
        gload16(lds + segb * 8, src + (long long)r * ld + k0 + qg * 8);
    }
}
__device__ __forceinline__ bf16x8 frag64(const u16* lds, int row, int quad, int kw) {
    const int slot = (kw * 4 + quad) ^ (row & 7);
    return __builtin_bit_cast(bf16x8, *(const u16x8*)(lds + row * BK2 + slot * 8));
}

// Counted-vmcnt barrier pair (T4, verified R10). Steady state: 4 loads/thread
// per tile-set; wait for the previous 4 while the new 4 stay in flight.
#define WAIT4_BARRIER()  asm volatile("s_waitcnt vmcnt(4)\n\ts_barrier" ::: "memory")
#define WAIT0_BARRIER()  asm volatile("s_waitcnt vmcnt(0)\n\ts_barrier" ::: "memory")
#define BARRIER()        asm volatile("s_barrier" ::: "memory")

// ---------- emulated-fp32 GEMM, 3 terms interleaved per K-tile ----------
// acc += Al*Bh + Ah*Bl + Ah*Bh per tile (K-order per element unchanged since
// R7). 512 threads, 8 waves as 2M x 4N (64x32 per wave), acc[4][2].
template<bool SPLITOUT>
__global__ void gemm_cat3(const u16* __restrict__ Ah, const u16* __restrict__ Al,
                          const u16* __restrict__ Bh, const u16* __restrict__ Bl,
                          const float* __restrict__ bias,
                          void* __restrict__ C, u16* __restrict__ Cl,
                          int K, long long lda, long long ldb, long long ldc,
                          int xcx, long long abstride, long long bbstride,
                          long long cbstride)
{
    __shared__ u16 sm[2][4][TILE];   // 64KB
    const int t = threadIdx.x;
    const int wave = t >> 6, lane = t & 63, quad = lane >> 4, l16 = lane & 15;
    const int waveM = (wave & 1) * 64, waveN = (wave >> 1) * 32;
    const int batch = blockIdx.z;
    Ah += batch * abstride; Al += batch * abstride;
    Bh += batch * bbstride; Bl += batch * bbstride;
    void* Cb = SPLITOUT ? C : (void*)((float*)C + (long long)batch * cbstride);
    int bx, by;
    remap_xy(xcx, bx, by);
    const long long rowBase = (long long)by * BM;
    const long long colBase = (long long)bx * BN;
    Ah += rowBase * lda; Al += rowBase * lda;
    Bh += colBase * ldb; Bl += colBase * ldb;

    f32x4 acc[4][2];
#pragma unroll
    for (int i = 0; i < 4; ++i)
#pragma unroll
        for (int j = 0; j < 2; ++j) acc[i][j] = (f32x4){0.f, 0.f, 0.f, 0.f};

    auto stage4 = [&](int buf, int k0) {   // 4 gload16 per thread
        stage_tile(sm[buf][0], Ah, lda, k0, wave, lane);
        stage_tile(sm[buf][1], Al, lda, k0, wave, lane);
        stage_tile(sm[buf][2], Bh, ldb, k0, wave, lane);
        stage_tile(sm[buf][3], Bl, ldb, k0, wave, lane);
    };

    stage4(0, 0);
    int cur = 0;
    for (int k0 = 0; k0 < K; k0 += BK) {
        if (k0 + BK < K) {
            stage4(cur ^ 1, k0 + BK);
            WAIT4_BARRIER();
        } else {
            WAIT0_BARRIER();
        }

        bf16x8 ah[4], al[4], bh[2], bl[2];
#pragma unroll
        for (int mi = 0; mi < 4; ++mi) {
            int row = waveM + mi * 16 + l16;
            ah[mi] = frag(sm[cur][0], row, quad);
            al[mi] = frag(sm[cur][1], row, quad);
        }
#pragma unroll
        for (int ni = 0; ni < 2; ++ni) {
            int row = waveN + ni * 16 + l16;
            bh[ni] = frag(sm[cur][2], row, quad);
            bl[ni] = frag(sm[cur][3], row, quad);
        }
#pragma unroll
        for (int mi = 0; mi < 4; ++mi)
#pragma unroll
            for (int ni = 0; ni < 2; ++ni) {
                acc[mi][ni] = __builtin_amdgcn_mfma_f32_16x16x32_bf16(al[mi], bh[ni], acc[mi][ni], 0, 0, 0);
                acc[mi][ni] = __builtin_amdgcn_mfma_f32_16x16x32_bf16(ah[mi], bl[ni], acc[mi][ni], 0, 0, 0);
                acc[mi][ni] = __builtin_amdgcn_mfma_f32_16x16x32_bf16(ah[mi], bh[ni], acc[mi][ni], 0, 0, 0);
            }

        BARRIER();
        cur ^= 1;
    }

#pragma unroll
    for (int mi = 0; mi < 4; ++mi) {
#pragma unroll
        for (int ni = 0; ni < 2; ++ni) {
            long long col = colBase + waveN + ni * 16 + l16;
            float bv = bias ? bias[col] : 0.0f;
#pragma unroll
            for (int r = 0; r < 4; ++r) {
                long long row = rowBase + waveM + mi * 16 + quad * 4 + r;
                float f = acc[mi][ni][r] + bv;
                long long off = row * ldc + col;
                if (SPLITOUT) {
                    u16 h = f2bf(f);
                    ((u16*)Cb)[off] = h;
                    Cl[off] = f2bf(f - bf2f(h));
                } else {
                    ((float*)Cb)[off] = f;
                }
            }
        }
    }
}

// ---------- single-precision bf16 GEMM, BK=64, 512 threads ----------
template<bool OUTF32>
__global__ void gemm_bf(const u16* __restrict__ A, const u16* __restrict__ B,
                        const float* __restrict__ bias, void* __restrict__ C,
                        int K, long long lda, long long ldb, long long ldc,
                        int xcx)
{
    __shared__ u16 sm[2][2][TILE2];   // 64KB
    const int t = threadIdx.x;
    const int wave = t >> 6, lane = t & 63, quad = lane >> 4, l16 = lane & 15;
    const int waveM = (wave & 1) * 64, waveN = (wave >> 1) * 32;
    int bx, by;
    remap_xy(xcx, bx, by);
    const long long rowBase = (long long)by * BM;
    const long long colBase = (long long)bx * BN;
    A += rowBase * lda;
    B += colBase * ldb;

    f32x4 acc[4][2];
#pragma unroll
    for (int i = 0; i < 4; ++i)
#pragma unroll
        for (int j = 0; j < 2; ++j) acc[i][j] = (f32x4){0.f, 0.f, 0.f, 0.f};

    auto stage2 = [&](int buf, int k0) {   // 4 gload16 per thread
        stage_tile64(sm[buf][0], A, lda, k0, wave, lane);
        stage_tile64(sm[buf][1], B, ldb, k0, wave, lane);
    };

    stage2(0, 0);
    int cur = 0;
    for (int k0 = 0; k0 < K; k0 += BK2) {
        if (k0 + BK2 < K) {
            stage2(cur ^ 1, k0 + BK2);
            WAIT4_BARRIER();
        } else {
            WAIT0_BARRIER();
        }

#pragma unroll
        for (int kw = 0; kw < 2; ++kw) {
            bf16x8 af[4], bfr[2];
#pragma unroll
            for (int mi = 0; mi < 4; ++mi) af[mi]  = frag64(sm[cur][0], waveM + mi * 16 + l16, quad, kw);
#pragma unroll
            for (int ni = 0; ni < 2; ++ni) bfr[ni] = frag64(sm[cur][1], waveN + ni * 16 + l16, quad, kw);
#pragma unroll
            for (int mi = 0; mi < 4; ++mi)
#pragma unroll
                for (int ni = 0; ni < 2; ++ni)
                    acc[mi][ni] = __builtin_amdgcn_mfma_f32_16x16x32_bf16(af[mi], bfr[ni], acc[mi][ni], 0, 0, 0);
        }

        BARRIER();
        cur ^= 1;
    }

#pragma unroll
    for (int mi = 0; mi < 4; ++mi) {
#pragma unroll
        for (int ni = 0; ni < 2; ++ni) {
            long long col = colBase + waveN + ni * 16 + l16;
            float bv = bias ? bias[col] : 0.0f;
#pragma unroll
            for (int r = 0; r < 4; ++r) {
                long long row = rowBase + waveM + mi * 16 + quad * 4 + r;
                float f = acc[mi][ni][r] + bv;
                long long off = row * ldc + col;
                if (OUTF32) ((float*)C)[off] = f;
                else        ((u16*)C)[off] = f2bf(f);
            }
        }
    }
}

// ---------- PV GEMM, split-K z=4, no atomics, BK=64, XCD-aligned ----------
__global__ void gemm_pv(const u16* __restrict__ A, const u16* __restrict__ B,
                        float* __restrict__ part, int KSEG,
                        long long lda, long long ldb,
                        long long abstride, long long bbstride, long long pbstride)
{
    __shared__ u16 sm[2][2][TILE2];   // 64KB
    const int t = threadIdx.x;
    const int wave = t >> 6, lane = t & 63, quad = lane >> 4, l16 = lane & 15;
    const int waveM = (wave & 1) * 64, waveN = (wave >> 1) * 32;
    const int flat = (blockIdx.z * gridDim.y + blockIdx.y) * gridDim.x + blockIdx.x;
    const int xcd = flat & 7, i = flat >> 3;
    const int batch = i >> 5;
    const int j = i & 31;
    const int by = 2 * xcd + (j & 1);
    const int bx = (j >> 1) & 3;
    const int bz = j >> 3;
    A += batch * abstride; B += batch * bbstride; part += batch * pbstride;
    const long long rowBase = (long long)by * BM;
    const long long colBase = (long long)bx * BN;
    const int kbase = bz * KSEG;
    A += rowBase * lda;
    B += colBase * ldb;

    f32x4 acc[4][2];
#pragma unroll
    for (int i2 = 0; i2 < 4; ++i2)
#pragma unroll
        for (int j2 = 0; j2 < 2; ++j2) acc[i2][j2] = (f32x4){0.f, 0.f, 0.f, 0.f};

    auto stage2 = [&](int buf, int k0) {
        stage_tile64(sm[buf][0], A, lda, k0, wave, lane);
        stage_tile64(sm[buf][1], B, ldb, k0, wave, lane);
    };

    stage2(0, kbase);
    int cur = 0;
    for (int k0 = kbase; k0 < kbase + KSEG; k0 += BK2) {
        if (k0 + BK2 < kbase + KSEG) {
            stage2(cur ^ 1, k0 + BK2);
            WAIT4_BARRIER();
        } else {
            WAIT0_BARRIER();
        }

#pragma unroll
        for (int kw = 0; kw < 2; ++kw) {
            bf16x8 af[4], bfr[2];
#pragma unroll
            for (int mi = 0; mi < 4; ++mi) af[mi]  = frag64(sm[cur][0], waveM + mi * 16 + l16, quad, kw);
#pragma unroll
            for (int ni = 0; ni < 2; ++ni) bfr[ni] = frag64(sm[cur][1], waveN + ni * 16 + l16, quad, kw);
#pragma unroll
            for (int mi = 0; mi < 4; ++mi)
#pragma unroll
                for (int ni = 0; ni < 2; ++ni)
                    acc[mi][ni] = __builtin_amdgcn_mfma_f32_16x16x32_bf16(af[mi], bfr[ni], acc[mi][ni], 0, 0, 0);
        }

        BARRIER();
        cur ^= 1;
    }

#pragma unroll
    for (int mi = 0; mi < 4; ++mi) {
#pragma unroll
        for (int ni = 0; ni < 2; ++ni) {
            long long col = colBase + waveN + ni * 16 + l16;
#pragma unroll
            for (int r = 0; r < 4; ++r) {
                long long row = rowBase + waveM + mi * 16 + quad * 4 + r;
                part[row * 4096 + 2048 + bz * 512 + col] = acc[mi][ni][r];
            }
        }
    }
}

// Sum 4 z-partials per element, write bf16 Att. batch = blockIdx.x>>11.
__global__ void cvt_att(const float* __restrict__ Sc, u16* __restrict__ dst,
                        long long sbstride, long long dbstride)
{
    const int d = blockIdx.x, t = threadIdx.x;
    const int batch = d >> 11, row = d & 2047;
    const float* p = Sc + (long long)batch * sbstride + (long long)row * 4096 + 2048 + t * 4;
    float4 s0 = *(const float4*)(p);
    float4 s1 = *(const float4*)(p + 512);
    float4 s2 = *(const float4*)(p + 1024);
    float4 s3 = *(const float4*)(p + 1536);
    u16x4 v;
    v[0] = f2bf(s0.x + s1.x + s2.x + s3.x);
    v[1] = f2bf(s0.y + s1.y + s2.y + s3.y);
    v[2] = f2bf(s0.z + s1.z + s2.z + s3.z);
    v[3] = f2bf(s0.w + s1.w + s2.w + s3.w);
    *(u16x4*)(dst + (long long)batch * dbstride + (long long)row * 512 + t * 4) = v;
}

// ---------- fp32 -> bf16 hi/lo split, 8 elems/thread ----------
__global__ void split32(const float* __restrict__ src, u16* __restrict__ h,
                        u16* __restrict__ l, long long n)
{
    long long i = ((long long)blockIdx.x * blockDim.x + threadIdx.x) * 8;
    if (i >= n) return;
    float4 a = *(const float4*)(src + i);
    float4 b = *(const float4*)(src + i + 4);
    float v[8] = {a.x, a.y, a.z, a.w, b.x, b.y, b.z, b.w};
    u16x8 hv, lv;
#pragma unroll
    for (int j = 0; j < 8; ++j) {
        u16 hh = f2bf(v[j]);
        hv[j] = hh;
        lv[j] = f2bf(v[j] - bf2f(hh));
    }
    *(u16x8*)(h + i) = hv;
    *(u16x8*)(l + i) = lv;
}

// ---------- fp32 -> bf16 (hi only), 8 elems/thread ----------
__global__ void cvt32(const float* __restrict__ src, u16* __restrict__ dst, long long n)
{
    long long i = ((long long)blockIdx.x * blockDim.x + threadIdx.x) * 8;
    if (i >= n) return;
    float4 a = *(const float4*)(src + i);
    float4 b = *(const float4*)(src + i + 4);
    u16x8 v;
    v[0] = f2bf(a.x); v[1] = f2bf(a.y); v[2] = f2bf(a.z); v[3] = f2bf(a.w);
    v[4] = f2bf(b.x); v[5] = f2bf(b.y); v[6] = f2bf(b.z); v[7] = f2bf(b.w);
    *(u16x8*)(dst + i) = v;
}

// Fused per-batch memory prep (batch = blockIdx.z).
__global__ void prep_mem(const float* __restrict__ src, u16* __restrict__ h,
                         u16* __restrict__ l, u16* __restrict__ tdst,
                         long long sstride, long long mstride, long long tstride)
{
    __shared__ u16 tile[64][72];
    const int batch = blockIdx.z;
    src += batch * sstride; h += batch * mstride; l += batch * mstride;
    tdst += batch * tstride;
    const int dBase = blockIdx.x * 64, mBase = blockIdx.y * 64;
    const int t = threadIdx.x;
#pragma unroll
    for (int i = 0; i < 4; ++i) {
        int seg = t + i * 256;
        int r = seg >> 4;                 // m-local
        int c = (seg & 15) << 2;          // d-local
        long long off = (long long)(mBase + r) * 512 + dBase + c;
        float4 v = *(const float4*)(src + off);
        u16 h0 = f2bf(v.x), h1 = f2bf(v.y), h2 = f2bf(v.z), h3 = f2bf(v.w);
        tile[r][c] = h0; tile[r][c + 1] = h1; tile[r][c + 2] = h2; tile[r][c + 3] = h3;
        u16x4 hv; hv[0] = h0; hv[1] = h1; hv[2] = h2; hv[3] = h3;
        u16x4 lv;
        lv[0] = f2bf(v.x - bf2f(h0)); lv[1] = f2bf(v.y - bf2f(h1));
        lv[2] = f2bf(v.z - bf2f(h2)); lv[3] = f2bf(v.w - bf2f(h3));
        *(u16x4*)(h + off) = hv;
        *(u16x4*)(l + off) = lv;
    }
    __syncthreads();
#pragma unroll
    for (int i = 0; i < 2; ++i) {
        int seg = t + i * 256;
        int r = seg >> 3;          // d-local
        int c = (seg & 7) << 3;    // m-local
        u16x8 v;
#pragma unroll
        for (int j = 0; j < 8; ++j) v[j] = tile[c + j][r];
        *(u16x8*)(tdst + (long long)(dBase + r) * 4096 + mBase + c) = v;
    }
}

// One block per score row; batch = blockIdx.x>>11; within-batch block d
// handles row (d&7)*256 + (d>>3) (XCD-aligned with gemm_pv's reader).
__global__ void softmax_rows(float* __restrict__ S, long long bstride)
{
    const int d = blockIdx.x;
    const int local = d & 2047, batch = d >> 11;
    const int rowIdx = (local & 7) * 256 + (local >> 3);
    float* p = S + (long long)batch * bstride + (long long)rowIdx * 4096;
    const int t = threadIdx.x;

    float4 v[4];
#pragma unroll
    for (int i = 0; i < 4; ++i) v[i] = ((const float4*)p)[t + i * 256];

    float m = -1e30f;
#pragma unroll
    for (int i = 0; i < 4; ++i)
        m = fmaxf(m, fmaxf(fmaxf(v[i].x, v[i].y), fmaxf(v[i].z, v[i].w)));
#pragma unroll
    for (int off = 32; off; off >>= 1) m = fmaxf(m, __shfl_xor(m, off));
    __shared__ float redm[4];
    if ((t & 63) == 0) redm[t >> 6] = m;
    __syncthreads();
    m = fmaxf(fmaxf(redm[0], redm[1]), fmaxf(redm[2], redm[3]));

    float s = 0.f;
#pragma unroll
    for (int i = 0; i < 4; ++i) {
        v[i].x = __expf(v[i].x - m); v[i].y = __expf(v[i].y - m);
        v[i].z = __expf(v[i].z - m); v[i].w = __expf(v[i].w - m);
        s += v[i].x + v[i].y + v[i].z + v[i].w;
    }
#pragma unroll
    for (int off = 32; off; off >>= 1) s += __shfl_xor(s, off);
    __shared__ float reds[4];
    if ((t & 63) == 0) reds[t >> 6] = s;
    __syncthreads();
    s = reds[0] + reds[1] + reds[2] + reds[3];
    const float inv = 1.0f / s;

    u16* pw = (u16*)p;
#pragma unroll
    for (int i = 0; i < 4; ++i) {
        u16x4 w;
        w[0] = f2bf(v[i].x * inv); w[1] = f2bf(v[i].y * inv);
        w[2] = f2bf(v[i].z * inv); w[3] = f2bf(v[i].w * inv);
        *(u16x4*)(pw + 4 * (t + i * 256)) = w;
    }
}

extern "C" void kernel_launch(void* const* d_in, const int* in_sizes, int n_in,
                              void* d_out, int out_size, void* d_ws, size_t ws_size,
                              hipStream_t stream)
{
    const float* x   = (const float*)d_in[0];   // [4,2048,1024] fp32
    const float* mem = (const float*)d_in[1];   // [4,4096,512]  fp32
    const float* Wq  = (const float*)d_in[2];   // [512,1024]    fp32
    const float* bq  = (const float*)d_in[3];   // [512]         fp32
    const float* Wm  = (const float*)d_in[4];   // [1024,512]    fp32
    const float* bm  = (const float*)d_in[5];   // [1024]        fp32

    char* base = (char*)d_out;
    u16*   Qh   = (u16*)base;
    u16*   Ql   = (u16*)(base + (8ll  << 20));
    u16*   Mh   = (u16*)(base + (16ll << 20));
    u16*   Ml   = (u16*)(base + (20ll << 20));
    u16*   MemT = (u16*)(base + (24ll << 20));
    u16*   Wqh  = (u16*)(base + (28ll << 20));
    u16*   Wql  = (u16*)(base + (29ll << 20));
    u16*   Wmh  = (u16*)(base + (30ll << 20));
    u16*   Xh   = (u16*)(base + (32ll << 20));
    u16*   Xl   = (u16*)(base + (48ll << 20));
    float* Sc   = (float*)(base + (32ll << 20));
    float* out1 = (float*)d_out + 8388608ll;

    // one-time hi/lo splits
    split32<<<4096, 256, 0, stream>>>(x,  Xh,  Xl,  8192ll * 1024);
    split32<<<256,  256, 0, stream>>>(Wq, Wqh, Wql, 512ll * 1024);
    cvt32<<<256,    256, 0, stream>>>(Wm, Wmh,      1024ll * 512);

    // Qh/Ql = split(x @ Wq^T + bq)   [8192,512], K=1024; grid (4,64), 512T
    gemm_cat3<true><<<dim3(512 / BN, 8192 / BM, 1), 512, 0, stream>>>(
        Xh, Xl, Wqh, Wql, bq, Qh, Ql, 1024, 1024, 1024, 512, 1, 0, 0, 0);

    // Batched attention path (verified R12: -63us) using d_ws (176MB).
    const bool big_ws = (d_ws != nullptr) && (ws_size >= (176ull << 20));
    if (big_ws) {
        char* wsb = (char*)d_ws;
        u16*   Mh4 = (u16*)wsb;                    // [4][4096,512]
        u16*   Ml4 = (u16*)(wsb + (16ll << 20));   // [4][4096,512]
        u16*   MT4 = (u16*)(wsb + (32ll << 20));   // [4][512,4096]
        float* Sc4 = (float*)(wsb + (48ll << 20)); // [4][2048,4096]

        prep_mem<<<dim3(8, 64, 4), 256, 0, stream>>>(
            mem, Mh4, Ml4, MT4, 4096ll * 512, 4096ll * 512, 512ll * 4096);

        gemm_cat3<false><<<dim3(4096 / BN, 2048 / BM, 4), 512, 0, stream>>>(
            Qh, Ql, Mh4, Ml4, nullptr, Sc4, nullptr, 512, 512, 512, 4096, 4,
            2048ll * 512, 4096ll * 512, 2048ll * 4096);

        softmax_rows<<<dim3(8192), 256, 0, stream>>>(Sc4, 2048ll * 4096);

        gemm_pv<<<dim3(4, 16, 16), 512, 0, stream>>>(
            (const u16*)Sc4, MT4, Sc4, 1024, 8192, 4096,
            2048ll * 8192, 512ll * 4096, 2048ll * 4096);

        cvt_att<<<dim3(8192), 128, 0, stream>>>(
            Sc4, Qh, 2048ll * 4096, 2048ll * 512);
    } else {
        for (int b = 0; b < 4; ++b) {
            const float* Mb = mem + (long long)b * 4096 * 512;
            u16* Qhb = Qh + (long long)b * 2048 * 512;
            u16* Qlb = Ql + (long long)b * 2048 * 512;

            prep_mem<<<dim3(8, 64, 1), 256, 0, stream>>>(
                Mb, Mh, Ml, MemT, 0, 0, 0);

            gemm_cat3<false><<<dim3(4096 / BN, 2048 / BM, 1), 512, 0, stream>>>(
                Qhb, Qlb, Mh, Ml, nullptr, Sc, nullptr, 512, 512, 512, 4096, 4,
                0, 0, 0);

            softmax_rows<<<dim3(2048), 256, 0, stream>>>(Sc, 0);

            gemm_pv<<<dim3(4, 16, 4), 512, 0, stream>>>(
                (const u16*)Sc, MemT, Sc, 1024, 8192, 4096, 0, 0, 0);

            cvt_att<<<dim3(2048), 128, 0, stream>>>(Sc, Qhb, 0, 0);
        }
    }

    // out1 = Att @ Wm^T + bm   [8192,1024], K=512; grid (8,64), 512T
    gemm_bf<true><<<dim3(1024 / BN, 8192 / BM, 1), 512, 0, stream>>>(
        Qh, Wmh, bm, out1, 512, 512, 512, 1024, 1);

    // out0 = x (exact fp32 copy; overwrites dead scratch). Must be last.
    hipMemcpyAsync(d_out, x, 8192ll * 1024 * 4, hipMemcpyDeviceToDevice, stream);
}